// Round 20
// baseline (192.842 us; speedup 1.0000x reference)
//
#include <hip/hip_runtime.h>
#include <math.h>

#define T_ 32
#define B_ 16
#define V_ 30000
#define V4 7500
#define D_ 300
#define DQKV_ 150
#define K_ 10
#define G_ 32
#define N_ 320                // K*G
#define S_ 25000
#define S4 6250
#define SLICE 3125            // S/8: SC row-range per XCD (3.75 MB = one L2)
#define QKP 304               // qk ws row stride (300 -> 304, 16B aligned)
#define NTS 1024              // scan threads
#define NTG 256               // gather threads
#define NTF 384               // finalize threads
#define NQB 32                // qkprep blocks
#define QROWS 16              // rows per qkprep block
#define LCAP 4096             // candidate list capacity (expect ~680 for N(0,1))
#define UTH 0xC0000000u       // u-map(2.0f): accept x >= 2.0

__device__ __forceinline__ unsigned umap(float f) {
    unsigned b = __float_as_uint(f);
    unsigned mask = (unsigned)(((int)b) >> 31);      // 0xFFFFFFFF if negative
    return b ^ (mask | 0x80000000u);                 // ascending uint == ascending float
}
__device__ __forceinline__ bool better_u(unsigned au, int ai, unsigned bu, int bi) {
    return (au > bu) || (au == bu && ai < bi);       // higher val, ties -> lower idx
}

// == Kernel 0: qkprep — Q = lc@Wq, QK = Q@Wk^T, 32 blocks x 16 rows ==========
//    Only 32 blocks touch Wq/Wk (vs 512) -> no L2 same-line storm.
__global__ __launch_bounds__(512) void qkprep_kernel(
    const float* __restrict__ lc, const float* __restrict__ Wq,
    const float* __restrict__ Wk, float* __restrict__ qkws)
{
    __shared__ __align__(16) float lcs[QROWS][304];   // 19.5 KB
    __shared__ float qlds[QROWS][152];                // 9.7 KB
    const int r0  = blockIdx.x * QROWS;
    const int tid = threadIdx.x;
    const int lane = tid & 63, wv = tid >> 6;

    // stage lc rows (contiguous 1200 float4)
    {
        const float4* src = (const float4*)(lc + (size_t)r0 * D_);
        for (int i = tid; i < QROWS * 75; i += 512) {
            int r = i / 75, c = i - r * 75;
            *(float4*)&lcs[r][c * 4] = src[i];
        }
    }
    __syncthreads();

    // Phase A: Q[r][j]; thread (j,h): j col, h half -> 8 rows each; Wq coalesced
    if (tid < 2 * DQKV_) {
        int j = tid % DQKV_, h = tid / DQKV_;
        float acc[8];
        #pragma unroll
        for (int rr = 0; rr < 8; ++rr) acc[rr] = 0.f;
        for (int d = 0; d < D_; ++d) {
            float w = Wq[(size_t)d * DQKV_ + j];
            #pragma unroll
            for (int rr = 0; rr < 8; ++rr) acc[rr] += lcs[h * 8 + rr][d] * w;
        }
        #pragma unroll
        for (int rr = 0; rr < 8; ++rr) qlds[h * 8 + rr][j] = acc[rr];
    }
    __syncthreads();

    // Phase B: QK[r][dd] = Q[r,:] . Wk[dd,:]; wave per dd, lanes split j,
    // 4-row interleaved shfl reduces
    for (int dd = wv; dd < D_; dd += 8) {
        const float* wr = Wk + (size_t)dd * DQKV_;
        float w0 = wr[lane];
        float w1 = wr[64 + lane];
        float w2 = (lane < 22) ? wr[128 + lane] : 0.f;
        #pragma unroll
        for (int rb = 0; rb < QROWS; rb += 4) {
            float p[4];
            #pragma unroll
            for (int i = 0; i < 4; ++i) {
                int r = rb + i;
                float q0 = qlds[r][lane];
                float q1 = qlds[r][64 + lane];
                float q2 = (lane < 22) ? qlds[r][128 + lane] : 0.f;
                p[i] = w0 * q0 + w1 * q1 + w2 * q2;
            }
            #pragma unroll
            for (int off = 32; off; off >>= 1) {
                #pragma unroll
                for (int i = 0; i < 4; ++i) p[i] += __shfl_xor(p[i], off, 64);
            }
            if (lane == 0) {
                #pragma unroll
                for (int i = 0; i < 4; ++i)
                    qkws[(size_t)(r0 + rb + i) * QKP + dd] = p[i];
            }
        }
    }
}

// == Kernel 1: fill + ballot-collect + 16-wave parallel top-10 -> wstop ======
__global__ __launch_bounds__(NTS, 2) void scan_kernel(
    const float* __restrict__ pred, float* __restrict__ out,
    int* __restrict__ wstop)
{
    const int row = blockIdx.x, tid = threadIdx.x;
    const int lane = tid & 63, wave = tid >> 6;
    __shared__ unsigned lu[LCAP];          // 16 KB candidate u-keys
    __shared__ int      li[LCAP];          // 16 KB candidate indices
    __shared__ int      cnt;
    __shared__ unsigned wcv[16 * K_];
    __shared__ int      wci[16 * K_];

    if (tid == 0) cnt = 0;
    __syncthreads();

    // fill output row with log(1e-8)
    const float FILL = -18.420680743952367f;
    {
        float4 f4 = make_float4(FILL, FILL, FILL, FILL);
        float4* o4 = (float4*)(out + (size_t)row * S_);
        #pragma unroll
        for (int k = 0; k < 7; ++k) { int i = tid + k * NTS; if (i < S4) o4[i] = f4; }
    }

    // stream row; ballot-aggregated collect (1 atomic per wave per component)
    {
        const float4* p4 = (const float4*)(pred + (size_t)row * V_);
        const float4 NEG = make_float4(-INFINITY, -INFINITY, -INFINITY, -INFINITY);
        float4 a[8]; int ib[8]; bool okf[8];
        #pragma unroll
        for (int u = 0; u < 8; ++u) {
            int i = tid + u * NTS;
            okf[u] = i < V4;
            a[u]  = okf[u] ? p4[i] : NEG;
            ib[u] = i * 4;
        }
        const unsigned long long lmask = (lane == 63) ? 0x7fffffffffffffffull
                                                      : ((1ull << lane) - 1ull);
        #pragma unroll
        for (int u = 0; u < 8; ++u) {
            float vals[4] = {a[u].x, a[u].y, a[u].z, a[u].w};
            #pragma unroll
            for (int c = 0; c < 4; ++c) {
                unsigned uu = umap(vals[c]);
                bool has = okf[u] && (uu >= UTH);
                unsigned long long mask = __ballot(has);
                if (mask) {
                    int bs = 0;
                    if (lane == 0) bs = atomicAdd(&cnt, (int)__popcll(mask));
                    bs = __shfl(bs, 0, 64);
                    if (has) {
                        int p = bs + (int)__popcll(mask & lmask);
                        if (p < LCAP) { lu[p] = uu; li[p] = ib[u] + c; }
                    }
                }
            }
        }
    }
    __syncthreads();
    const int c = cnt;
    const bool mainpath = (c >= K_ && c <= LCAP);

    if (mainpath) {
        // 16-wave parallel select: each wave top-10 of its strided subset
        unsigned cu[4]; int cix[4];
        #pragma unroll
        for (int k = 0; k < 4; ++k) {
            int s = wave * 64 + lane + k * NTS;
            bool ok = s < c;
            cu[k]  = ok ? lu[s] : 0u;
            cix[k] = ok ? li[s] : 0x7fffffff;
        }
        for (int p = 0; p < K_; ++p) {
            unsigned bu = cu[0]; int bi = cix[0];
            #pragma unroll
            for (int k = 1; k < 4; ++k)
                if (better_u(cu[k], cix[k], bu, bi)) { bu = cu[k]; bi = cix[k]; }
            #pragma unroll
            for (int off = 32; off; off >>= 1) {
                unsigned ou = __shfl_xor(bu, off, 64);
                int      oi = __shfl_xor(bi, off, 64);
                if (better_u(ou, oi, bu, bi)) { bu = ou; bi = oi; }
            }
            if (lane == 0) { wcv[wave * K_ + p] = bu; wci[wave * K_ + p] = bi; }
            #pragma unroll
            for (int k = 0; k < 4; ++k)
                if (cix[k] == bi) cu[k] = 0u;
        }
        __syncthreads();

        // wave 0 merges the 160 wave-winners
        if (wave == 0) {
            unsigned c0u = wcv[lane],      c1u = wcv[64 + lane];
            int      c0i = wci[lane],      c1i = wci[64 + lane];
            unsigned c2u = (lane < 32) ? wcv[128 + lane] : 0u;
            int      c2i = (lane < 32) ? wci[128 + lane] : 0x7fffffff;
            for (int p = 0; p < K_; ++p) {
                unsigned bu = c0u; int bi = c0i;
                if (better_u(c1u, c1i, bu, bi)) { bu = c1u; bi = c1i; }
                if (better_u(c2u, c2i, bu, bi)) { bu = c2u; bi = c2i; }
                #pragma unroll
                for (int off = 32; off; off >>= 1) {
                    unsigned ou = __shfl_xor(bu, off, 64);
                    int      oi = __shfl_xor(bi, off, 64);
                    if (better_u(ou, oi, bu, bi)) { bu = ou; bi = oi; }
                }
                if (lane == 0) wstop[row * K_ + p] = bi;
                if (c0i == bi) c0u = 0u;
                if (c1i == bi) c1u = 0u;
                if (c2i == bi) c2u = 0u;
            }
        }
    } else {
        // exact fallback (never triggers for N(0,1)): wave0 re-scans row
        if (wave == 0) {
            unsigned tu[K_]; int tix[K_];
            #pragma unroll
            for (int s = 0; s < K_; ++s) { tu[s] = 0; tix[s] = 0x7fffffff; }
            const float* prow = pred + (size_t)row * V_;
            for (int i = lane; i < V_; i += 64) {
                unsigned u = umap(prow[i]);
                if (better_u(u, i, tu[K_-1], tix[K_-1])) {
                    tu[K_-1] = u; tix[K_-1] = i;
                    #pragma unroll
                    for (int s = K_-1; s > 0; --s)
                        if (better_u(tu[s], tix[s], tu[s-1], tix[s-1])) {
                            unsigned a = tu[s]; tu[s] = tu[s-1]; tu[s-1] = a;
                            int b2 = tix[s]; tix[s] = tix[s-1]; tix[s-1] = b2;
                        }
                }
            }
            for (int p = 0; p < K_; ++p) {
                unsigned bu = tu[0]; int bi = tix[0];
                #pragma unroll
                for (int s = 1; s < K_; ++s)
                    if (better_u(tu[s], tix[s], bu, bi)) { bu = tu[s]; bi = tix[s]; }
                #pragma unroll
                for (int off = 32; off; off >>= 1) {
                    unsigned ou = __shfl_xor(bu, off, 64);
                    int      oi = __shfl_xor(bi, off, 64);
                    if (better_u(ou, oi, bu, bi)) { bu = ou; bi = oi; }
                }
                if (lane == 0) wstop[row * K_ + p] = bi;
                #pragma unroll
                for (int s = 0; s < K_; ++s)
                    if (tix[s] == bi) tu[s] = 0;
            }
        }
    }
}

// == Kernel 2: XCD-local gather (computes nidx from wstop+nbt itself) ========
__global__ __launch_bounds__(NTG) void gather_kernel(
    const float* __restrict__ SC, const float* __restrict__ qkws,
    const int* __restrict__ nbt, const int* __restrict__ wstop,
    float* __restrict__ logws)
{
    const int r = blockIdx.x >> 3;
    const int ch = blockIdx.x & 7;
    const int lo = ch * SLICE, hi = lo + SLICE;
    const int tid = threadIdx.x;
    __shared__ int   topg[K_];
    __shared__ int   nid[N_];
    __shared__ __align__(16) float qk[D_];
    __shared__ int   list[N_];
    __shared__ int   lcnt;

    if (tid == 0) lcnt = 0;
    if (tid < K_) topg[tid] = wstop[r * K_ + tid];
    if (tid >= 64 && tid < 64 + D_ / 4)
        ((float4*)qk)[tid - 64] = ((const float4*)(qkws + (size_t)r * QKP))[tid - 64];
    __syncthreads();

    for (int i = tid; i < N_; i += NTG)
        nid[i] = nbt[topg[i >> 5] * G_ + (i & 31)];
    __syncthreads();

    for (int i = tid; i < N_; i += NTG) {
        int sv = nid[i];
        if (sv >= lo && sv < hi) { int p = atomicAdd(&lcnt, 1); list[p] = i; }
    }
    __syncthreads();
    const int c2 = lcnt;

    const float ISC = 0.08164965809277260327f;   // 1/sqrt(150)
    const float4* q4 = (const float4*)qk;
    for (int s = tid; s < 8 * c2; s += NTG) {
        int g = s >> 3, h = s & 7;
        int n = list[g];
        const float4* sc4 = (const float4*)(SC + (size_t)nid[n] * D_);
        int c0 = h * 9;
        float acc = 0.f;
        #pragma unroll
        for (int cc = 0; cc < 9; ++cc) {
            float4 a = sc4[c0 + cc];
            float4 bq = q4[c0 + cc];
            acc += a.x * bq.x + a.y * bq.y + a.z * bq.z + a.w * bq.w;
        }
        if (h < 3) {
            float4 a = sc4[72 + h];
            float4 bq = q4[72 + h];
            acc += a.x * bq.x + a.y * bq.y + a.z * bq.z + a.w * bq.w;
        }
        acc += __shfl_xor(acc, 1, 64);
        acc += __shfl_xor(acc, 2, 64);
        acc += __shfl_xor(acc, 4, 64);
        if (h == 0) logws[(size_t)r * N_ + n] = acc * ISC;
    }
}

// == Kernel 3: softmax + last-write-wins dup-kill + scatter ===================
__global__ __launch_bounds__(NTF) void finalize_kernel(
    const float* __restrict__ logws, const int* __restrict__ nbt,
    const int* __restrict__ wstop, float* __restrict__ out)
{
    const int row = blockIdx.x, tid = threadIdx.x;
    const int lane = tid & 63, wave = tid >> 6;
    __shared__ int   topg[K_];
    __shared__ float lg[N_];
    __shared__ int   nid[N_];
    __shared__ int   kills[N_];
    __shared__ float redA[6], redB[6];
    float* outrow = out + (size_t)row * S_;

    if (tid < K_) topg[tid] = wstop[row * K_ + tid];
    __syncthreads();
    if (tid < N_) {
        nid[tid] = nbt[topg[tid >> 5] * G_ + (tid & 31)];
        lg[tid]  = logws[(size_t)row * N_ + tid];
        kills[tid] = 0;
    }
    __syncthreads();

    float v = (tid < N_) ? lg[tid] : -INFINITY;
    float m = v;
    #pragma unroll
    for (int off = 32; off; off >>= 1) m = fmaxf(m, __shfl_xor(m, off, 64));
    if (lane == 0) redA[wave] = m;
    __syncthreads();
    m = redA[0];
    #pragma unroll
    for (int w = 1; w < 6; ++w) m = fmaxf(m, redA[w]);

    float ss = (tid < N_) ? expf(v - m) : 0.f;
    #pragma unroll
    for (int off = 32; off; off >>= 1) ss += __shfl_xor(ss, off, 64);
    if (lane == 0) redB[wave] = ss;
    __syncthreads();
    float tot = redB[0];
    #pragma unroll
    for (int w = 1; w < 6; ++w) tot += redB[w];
    float lsum = logf(tot);

    for (int s = tid; s < 4 * N_; s += NTF) {
        int n = s >> 2, cix = s & 3;
        int sidx = nid[n];
        int clo = cix * 80;
        int lo2 = (n + 1 > clo) ? n + 1 : clo;
        int hi2 = clo + 80;
        bool mt = false;
        #pragma unroll 4
        for (int n2 = lo2; n2 < hi2; ++n2) mt |= (nid[n2] == sidx);
        if (mt) kills[n] = 1;
    }
    __syncthreads();

    if (tid < N_ && !kills[tid]) outrow[nid[tid]] = (v - m) - lsum;
}

// ================= Fallback: fused single kernel (needs no ws) ===============
#define NWS 16
__device__ __forceinline__ bool better(float av, int ai, float bv, int bi) {
    return (av > bv) || (av == bv && ai < bi);
}
__global__ __launch_bounds__(NTS, 4) void selfatt_fused(
    const float* __restrict__ pred, const float* __restrict__ lc,
    const float* __restrict__ SC, const float* __restrict__ Wq,
    const float* __restrict__ Wk, const int* __restrict__ nbt,
    float* __restrict__ out)
{
    const int row = blockIdx.x, tid = threadIdx.x;
    const int lane = tid & 63, wave = tid >> 6;
    __shared__ float wcv[NWS * K_];
    __shared__ int   wci[NWS * K_];
    __shared__ int   topg[K_];
    __shared__ float lcs[D_];
    __shared__ float qs[DQKV_];
    __shared__ __align__(16) float qks[D_];
    __shared__ int   nidx[N_];
    __shared__ float lg[N_];
    __shared__ int   kills[N_];
    __shared__ float redA[NWS], redB[NWS];
    float* outrow = out + (size_t)row * S_;
    const float FILL = -18.420680743952367f;
    {
        float4 f4 = make_float4(FILL, FILL, FILL, FILL);
        float4* o4 = (float4*)outrow;
        #pragma unroll
        for (int k = 0; k < 7; ++k) { int i = tid + k * NTS; if (i < S4) o4[i] = f4; }
    }
    float tv[K_]; int ti[K_];
    #pragma unroll
    for (int s = 0; s < K_; ++s) { tv[s] = -INFINITY; ti[s] = 0x7fffffff; }
    {
        const float4* p4 = (const float4*)(pred + (size_t)row * V_);
        const float4 NEG = make_float4(-INFINITY, -INFINITY, -INFINITY, -INFINITY);
        float4 a[8]; int ib[8];
        #pragma unroll
        for (int u = 0; u < 8; ++u) {
            int i = tid + u * NTS;
            a[u]  = (i < V4) ? p4[i] : NEG;
            ib[u] = (i < V4) ? i * 4 : 0x7ffffff0;
        }
        #pragma unroll
        for (int u = 0; u < 8; ++u) {
            float x = a[u].x, y = a[u].y, z = a[u].z, w = a[u].w;
            float m4 = fmaxf(fmaxf(x, y), fmaxf(z, w));
            if (!(m4 < tv[K_-1])) {
                float vals[4] = {x, y, z, w};
                #pragma unroll
                for (int cc = 0; cc < 4; ++cc) {
                    float val = vals[cc];
                    int   idx = ib[u] + cc;
                    if (better(val, idx, tv[K_-1], ti[K_-1])) {
                        tv[K_-1] = val; ti[K_-1] = idx;
                        #pragma unroll
                        for (int s = K_-1; s > 0; --s) {
                            if (better(tv[s], ti[s], tv[s-1], ti[s-1])) {
                                float fx = tv[s]; tv[s] = tv[s-1]; tv[s-1] = fx;
                                int   iy = ti[s]; ti[s] = ti[s-1]; ti[s-1] = iy;
                            }
                        }
                    }
                }
            }
        }
    }
    for (int p = 0; p < K_; ++p) {
        float bv = tv[0]; int bi = ti[0];
        #pragma unroll
        for (int s = 1; s < K_; ++s)
            if (better(tv[s], ti[s], bv, bi)) { bv = tv[s]; bi = ti[s]; }
        #pragma unroll
        for (int off = 32; off; off >>= 1) {
            float ov = __shfl_xor(bv, off, 64);
            int   oi = __shfl_xor(bi, off, 64);
            if (better(ov, oi, bv, bi)) { bv = ov; bi = oi; }
        }
        if (lane == 0) { wcv[wave * K_ + p] = bv; wci[wave * K_ + p] = bi; }
        #pragma unroll
        for (int s = 0; s < K_; ++s)
            if (ti[s] == bi) tv[s] = -INFINITY;
    }
    __syncthreads();
    if (wave == 0) {
        float c0v = wcv[lane],      c1v = wcv[64 + lane];
        int   c0i = wci[lane],      c1i = wci[64 + lane];
        float c2v = (lane < 32) ? wcv[128 + lane] : -INFINITY;
        int   c2i = (lane < 32) ? wci[128 + lane] : 0x7fffffff;
        for (int p = 0; p < K_; ++p) {
            float bv = c0v; int bi = c0i;
            if (better(c1v, c1i, bv, bi)) { bv = c1v; bi = c1i; }
            if (better(c2v, c2i, bv, bi)) { bv = c2v; bi = c2i; }
            #pragma unroll
            for (int off = 32; off; off >>= 1) {
                float ov = __shfl_xor(bv, off, 64);
                int   oi = __shfl_xor(bi, off, 64);
                if (better(ov, oi, bv, bi)) { bv = ov; bi = oi; }
            }
            if (lane == 0) topg[p] = bi;
            if (c0i == bi) c0v = -INFINITY;
            if (c1i == bi) c1v = -INFINITY;
            if (c2i == bi) c2v = -INFINITY;
        }
    }
    __syncthreads();
    if (tid < N_) { int g = topg[tid >> 5]; nidx[tid] = nbt[g * G_ + (tid & 31)]; }
    else if (tid < 2 * N_) kills[tid - N_] = 0;
    else if (tid >= 640 && tid < 640 + D_) lcs[tid - 640] = lc[(size_t)row * D_ + (tid - 640)];
    __syncthreads();
    if (tid < 600) {
        int j = tid >> 2, h = tid & 3;
        int d0 = h * 75;
        const float* wp = Wq + (size_t)d0 * DQKV_ + j;
        float acc = 0.f;
        #pragma unroll 5
        for (int dd = 0; dd < 75; ++dd) acc += lcs[d0 + dd] * wp[(size_t)dd * DQKV_];
        acc += __shfl_xor(acc, 1, 64);
        acc += __shfl_xor(acc, 2, 64);
        if (h == 0) qs[j] = acc;
    } else {
        int t0 = tid - 600;
        for (int s = t0; s < 4 * N_; s += 424) {
            int n = s >> 2, cc = s & 3;
            int sidx = nidx[n];
            int clo = cc * 80;
            int lo = (n + 1 > clo) ? n + 1 : clo;
            int hi = clo + 80;
            bool mt = false;
            #pragma unroll 4
            for (int n2 = lo; n2 < hi; ++n2) mt |= (nidx[n2] == sidx);
            if (mt) kills[n] = 1;
        }
    }
    __syncthreads();
    if (tid < 600) {
        int d = tid >> 1, h = tid & 1;
        int j0 = h * 75;
        const float* wrow = Wk + (size_t)d * DQKV_ + j0;
        float acc = 0.f;
        #pragma unroll 5
        for (int jj = 0; jj < 75; ++jj) acc += wrow[jj] * qs[j0 + jj];
        acc += __shfl_xor(acc, 1, 64);
        if (h == 0) qks[d] = acc;
    }
    __syncthreads();
    const float ISC = 0.08164965809277260327f;
    const float4* q4 = (const float4*)qks;
    for (int s = tid; s < 8 * N_; s += NTS) {
        int n = s >> 3, h = s & 7;
        const float4* sc4 = (const float4*)(SC + (size_t)nidx[n] * D_);
        int c0 = h * 9;
        float acc = 0.f;
        #pragma unroll
        for (int cc = 0; cc < 9; ++cc) {
            float4 a = sc4[c0 + cc];
            float4 b = q4[c0 + cc];
            acc += a.x * b.x + a.y * b.y + a.z * b.z + a.w * b.w;
        }
        if (h < 3) {
            float4 a = sc4[72 + h];
            float4 b = q4[72 + h];
            acc += a.x * b.x + a.y * b.y + a.z * b.z + a.w * b.w;
        }
        acc += __shfl_xor(acc, 1, 64);
        acc += __shfl_xor(acc, 2, 64);
        acc += __shfl_xor(acc, 4, 64);
        if (h == 0) lg[n] = acc * ISC;
    }
    __syncthreads();
    float v = (tid < N_) ? lg[tid] : -INFINITY;
    float m = v;
    #pragma unroll
    for (int off = 32; off; off >>= 1) m = fmaxf(m, __shfl_xor(m, off, 64));
    if (lane == 0) redA[wave] = m;
    __syncthreads();
    m = redA[0];
    #pragma unroll
    for (int w = 1; w < NWS; ++w) m = fmaxf(m, redA[w]);
    float e = (tid < N_) ? expf(v - m) : 0.f;
    float ss = e;
    #pragma unroll
    for (int off = 32; off; off >>= 1) ss += __shfl_xor(ss, off, 64);
    if (lane == 0) redB[wave] = ss;
    __syncthreads();
    float tot = redB[0];
    #pragma unroll
    for (int w = 1; w < NWS; ++w) tot += redB[w];
    float lsum = logf(tot);
    if (tid < N_ && !kills[tid]) outrow[nidx[tid]] = (v - m) - lsum;
}

extern "C" void kernel_launch(void* const* d_in, const int* in_sizes, int n_in,
                              void* d_out, int out_size, void* d_ws, size_t ws_size,
                              hipStream_t stream) {
    const float* pred = (const float*)d_in[0];
    const float* lc   = (const float*)d_in[1];
    const float* SC   = (const float*)d_in[2];
    const float* Wq   = (const float*)d_in[3];
    const float* Wk   = (const float*)d_in[4];
    const int*   nbt  = (const int*)d_in[5];
    float* out = (float*)d_out;

    const int nrows = T_ * B_;
    const size_t nQK = (size_t)nrows * QKP;            // floats
    const size_t nLG = (size_t)nrows * N_;             // floats
    const size_t nTP = (size_t)nrows * K_;             // ints (wstop)
    const size_t need = (nQK + nLG) * sizeof(float) + nTP * sizeof(int);

    if (ws_size >= need) {
        float* qkws  = (float*)d_ws;
        float* logws = qkws + nQK;
        int*   wstop = (int*)(logws + nLG);
        qkprep_kernel<<<dim3(NQB), dim3(512), 0, stream>>>(lc, Wq, Wk, qkws);
        scan_kernel<<<dim3(nrows), dim3(NTS), 0, stream>>>(pred, out, wstop);
        gather_kernel<<<dim3(nrows * 8), dim3(NTG), 0, stream>>>(
            SC, qkws, nbt, wstop, logws);
        finalize_kernel<<<dim3(nrows), dim3(NTF), 0, stream>>>(
            logws, nbt, wstop, out);
    } else {
        selfatt_fused<<<dim3(T_ * B_), dim3(NTS), 0, stream>>>(
            pred, lc, SC, Wq, Wk, nbt, out);
    }
}

// Round 21
// 116.211 us; speedup vs baseline: 1.6594x; 1.6594x over previous
//
#include <hip/hip_runtime.h>
#include <math.h>

#define T_ 32
#define B_ 16
#define V_ 30000
#define V4 7500
#define H4P 3750              // pred float4 per half row
#define D_ 300
#define DQKV_ 150
#define K_ 10
#define G_ 32
#define N_ 320                // K*G
#define S_ 25000
#define S4 6250
#define F4H 3125              // out-fill float4 per half row
#define SLICE 3125            // S/8: SC row-range per XCD (3.75 MB = one L2)
#define QKP 304               // qk ws row stride (300 -> 304, 16B aligned)
#define NT1 256               // stage1 threads
#define NSCAN 1024            // half-row scan blocks
#define NQK 512               // qk blocks (one per row)
#define NTG 256               // gather threads
#define NTF 384               // finalize threads
#define LCAP2 2048            // per-half candidate cap (expect ~340)
#define UTH 0xC0000000u       // u-map(2.0f): accept x >= 2.0

__device__ __forceinline__ unsigned umap(float f) {
    unsigned b = __float_as_uint(f);
    unsigned mask = (unsigned)(((int)b) >> 31);      // 0xFFFFFFFF if negative
    return b ^ (mask | 0x80000000u);                 // ascending uint == ascending float
}
__device__ __forceinline__ bool better_u(unsigned au, int ai, unsigned bu, int bi) {
    return (au > bu) || (au == bu && ai < bi);       // higher val, ties -> lower idx
}

// == Kernel 1 (stage1, homogeneous 256-thread blocks):
//    [0,NSCAN):        half-row fill + ballot-collect + 4-wave top-10 -> ws(u,i)
//    [NSCAN,+NQK):     per-row q = lc@Wq, qk = Wk@q -> qkws (coalesced)
__global__ __launch_bounds__(NT1, 6) void stage1_kernel(
    const float* __restrict__ pred, const float* __restrict__ lc,
    const float* __restrict__ Wq, const float* __restrict__ Wk,
    float* __restrict__ out, unsigned* __restrict__ wsu, int* __restrict__ wsi,
    float* __restrict__ qkws)
{
    const int b = blockIdx.x, tid = threadIdx.x;
    const int lane = tid & 63, wave = tid >> 6;

    if (b >= NSCAN) {
        // ---------------- qk path: one row per block ----------------
        const int row = b - NSCAN;
        __shared__ __align__(16) float lcs[D_];
        __shared__ float qpart[2][DQKV_];
        if (tid < D_ / 4)
            ((float4*)lcs)[tid] = ((const float4*)(lc + (size_t)row * D_))[tid];
        __syncthreads();

        // q-partials: 300 units strided; Wq loads coalesced in j
        for (int t = tid; t < 2 * DQKV_; t += NT1) {
            int h = t / DQKV_;
            int j = t - h * DQKV_;
            int d0 = h * 150;
            const float* wp = Wq + (size_t)d0 * DQKV_ + j;
            float a0 = 0.f, a1 = 0.f;
            #pragma unroll 5
            for (int dd = 0; dd < 150; dd += 2) {
                a0 += lcs[d0 + dd]     * wp[(size_t)dd * DQKV_];
                a1 += lcs[d0 + dd + 1] * wp[(size_t)(dd + 1) * DQKV_];
            }
            qpart[h][j] = a0 + a1;
        }
        __syncthreads();

        // qk[d] = Wk[d,:] . q — wave per d-row (4 waves x 75 rows), coalesced
        float qv0 = qpart[0][lane] + qpart[1][lane];
        float qv1 = qpart[0][64 + lane] + qpart[1][64 + lane];
        float qv2 = (lane < 22) ? (qpart[0][128 + lane] + qpart[1][128 + lane]) : 0.f;
        for (int d = wave; d < D_; d += 4) {
            const float* wr = Wk + (size_t)d * DQKV_;
            float w0 = wr[lane];
            float w1 = wr[64 + lane];
            float w2 = (lane < 22) ? wr[128 + lane] : 0.f;
            float p = w0 * qv0 + w1 * qv1 + w2 * qv2;
            #pragma unroll
            for (int off = 32; off; off >>= 1) p += __shfl_xor(p, off, 64);
            if (lane == 0) qkws[(size_t)row * QKP + d] = p;
        }
        return;
    }

    // ---------------- scan path: half-row ----------------
    const int row  = b >> 1;
    const int half = b & 1;
    __shared__ unsigned lu[LCAP2];         // 8 KB candidate u-keys
    __shared__ int      li[LCAP2];         // 8 KB candidate indices
    __shared__ int      cnt;
    __shared__ unsigned wcv[4 * K_];
    __shared__ int      wci[4 * K_];

    if (tid == 0) cnt = 0;
    __syncthreads();

    // fill this half of the output row with log(1e-8)
    const float FILL = -18.420680743952367f;
    {
        float4 f4 = make_float4(FILL, FILL, FILL, FILL);
        float4* o4 = (float4*)(out + (size_t)row * S_) + half * F4H;
        for (int i = tid; i < F4H; i += NT1) o4[i] = f4;
    }

    // stream half-row; ballot-aggregated collect
    {
        const float4* p4 = (const float4*)(pred + (size_t)row * V_) + half * H4P;
        const int gbase = half * (H4P * 4);
        const unsigned long long lmask = (lane == 63) ? 0x7fffffffffffffffull
                                                      : ((1ull << lane) - 1ull);
        for (int t = 0; t < 5; ++t) {                 // 15 f4/thread, staged 3
            float4 a[3]; int ib[3]; bool okf[3];
            #pragma unroll
            for (int u = 0; u < 3; ++u) {
                int i = tid + (t * 3 + u) * NT1;
                okf[u] = i < H4P;
                a[u]  = okf[u] ? p4[i]
                               : make_float4(-INFINITY, -INFINITY, -INFINITY, -INFINITY);
                ib[u] = gbase + i * 4;
            }
            #pragma unroll
            for (int u = 0; u < 3; ++u) {
                float vals[4] = {a[u].x, a[u].y, a[u].z, a[u].w};
                #pragma unroll
                for (int c = 0; c < 4; ++c) {
                    unsigned uu = umap(vals[c]);
                    bool has = okf[u] && (uu >= UTH);
                    unsigned long long mask = __ballot(has);
                    if (mask) {
                        int bs = 0;
                        if (lane == 0) bs = atomicAdd(&cnt, (int)__popcll(mask));
                        bs = __shfl(bs, 0, 64);
                        if (has) {
                            int p = bs + (int)__popcll(mask & lmask);
                            if (p < LCAP2) { lu[p] = uu; li[p] = ib[u] + c; }
                        }
                    }
                }
            }
        }
    }
    __syncthreads();
    const int c = cnt;

    if (c >= K_ && c <= LCAP2) {
        // 4-wave parallel select: each wave top-10 of its strided subset
        unsigned cu[8]; int cix[8];
        #pragma unroll
        for (int k = 0; k < 8; ++k) {
            int s = wave * 64 + lane + k * NT1;
            bool ok = s < c;
            cu[k]  = ok ? lu[s] : 0u;
            cix[k] = ok ? li[s] : 0x7fffffff;
        }
        for (int p = 0; p < K_; ++p) {
            unsigned bu = cu[0]; int bi = cix[0];
            #pragma unroll
            for (int k = 1; k < 8; ++k)
                if (better_u(cu[k], cix[k], bu, bi)) { bu = cu[k]; bi = cix[k]; }
            #pragma unroll
            for (int off = 32; off; off >>= 1) {
                unsigned ou = __shfl_xor(bu, off, 64);
                int      oi = __shfl_xor(bi, off, 64);
                if (better_u(ou, oi, bu, bi)) { bu = ou; bi = oi; }
            }
            if (lane == 0) { wcv[wave * K_ + p] = bu; wci[wave * K_ + p] = bi; }
            #pragma unroll
            for (int k = 0; k < 8; ++k)
                if (cix[k] == bi) cu[k] = 0u;
        }
        __syncthreads();

        // wave 0 merges the 40 wave-winners -> half top-10 -> ws
        if (wave == 0) {
            unsigned cv = (lane < 40) ? wcv[lane] : 0u;
            int      ci = (lane < 40) ? wci[lane] : 0x7fffffff;
            for (int p = 0; p < K_; ++p) {
                unsigned bu = cv; int bi = ci;
                #pragma unroll
                for (int off = 32; off; off >>= 1) {
                    unsigned ou = __shfl_xor(bu, off, 64);
                    int      oi = __shfl_xor(bi, off, 64);
                    if (better_u(ou, oi, bu, bi)) { bu = ou; bi = oi; }
                }
                if (lane == 0) {
                    wsu[(row * 2 + half) * K_ + p] = bu;
                    wsi[(row * 2 + half) * K_ + p] = bi;
                }
                if (ci == bi) cv = 0u;
            }
        }
    } else {
        // exact fallback (never triggers for N(0,1)): wave0 serial-scans half
        if (wave == 0) {
            unsigned tu[K_]; int tix[K_];
            #pragma unroll
            for (int s = 0; s < K_; ++s) { tu[s] = 0; tix[s] = 0x7fffffff; }
            const float* prow = pred + (size_t)row * V_ + half * (H4P * 4);
            const int gbase = half * (H4P * 4);
            for (int i = lane; i < H4P * 4; i += 64) {
                unsigned u = umap(prow[i]);
                int gi = gbase + i;
                if (better_u(u, gi, tu[K_-1], tix[K_-1])) {
                    tu[K_-1] = u; tix[K_-1] = gi;
                    #pragma unroll
                    for (int s = K_-1; s > 0; --s)
                        if (better_u(tu[s], tix[s], tu[s-1], tix[s-1])) {
                            unsigned a = tu[s]; tu[s] = tu[s-1]; tu[s-1] = a;
                            int b2 = tix[s]; tix[s] = tix[s-1]; tix[s-1] = b2;
                        }
                }
            }
            for (int p = 0; p < K_; ++p) {
                unsigned bu = tu[0]; int bi = tix[0];
                #pragma unroll
                for (int s = 1; s < K_; ++s)
                    if (better_u(tu[s], tix[s], bu, bi)) { bu = tu[s]; bi = tix[s]; }
                #pragma unroll
                for (int off = 32; off; off >>= 1) {
                    unsigned ou = __shfl_xor(bu, off, 64);
                    int      oi = __shfl_xor(bi, off, 64);
                    if (better_u(ou, oi, bu, bi)) { bu = ou; bi = oi; }
                }
                if (lane == 0) {
                    wsu[(row * 2 + half) * K_ + p] = bu;
                    wsi[(row * 2 + half) * K_ + p] = bi;
                }
                #pragma unroll
                for (int s = 0; s < K_; ++s)
                    if (tix[s] == bi) tu[s] = 0;
            }
        }
    }
}

// one-wave merge of a row's 2x10 half-candidates -> topg[10] in LDS
__device__ __forceinline__ void merge20(
    const unsigned* __restrict__ wsu, const int* __restrict__ wsi,
    int row, int lane, int* topg)
{
    unsigned cv = (lane < 2 * K_) ? wsu[row * 2 * K_ + lane] : 0u;
    int      ci = (lane < 2 * K_) ? wsi[row * 2 * K_ + lane] : 0x7fffffff;
    for (int p = 0; p < K_; ++p) {
        unsigned bu = cv; int bi = ci;
        #pragma unroll
        for (int off = 32; off; off >>= 1) {
            unsigned ou = __shfl_xor(bu, off, 64);
            int      oi = __shfl_xor(bi, off, 64);
            if (better_u(ou, oi, bu, bi)) { bu = ou; bi = oi; }
        }
        if (lane == 0) topg[p] = bi;
        if (ci == bi) cv = 0u;
    }
}

// == Kernel 2: XCD-local gather (merges halves, computes nidx from nbt) ======
__global__ __launch_bounds__(NTG) void gather_kernel(
    const float* __restrict__ SC, const float* __restrict__ qkws,
    const int* __restrict__ nbt, const unsigned* __restrict__ wsu,
    const int* __restrict__ wsi, float* __restrict__ logws)
{
    const int r = blockIdx.x >> 3;
    const int ch = blockIdx.x & 7;
    const int lo = ch * SLICE, hi = lo + SLICE;
    const int tid = threadIdx.x;
    const int lane = tid & 63, wave = tid >> 6;
    __shared__ int   topg[K_];
    __shared__ int   nid[N_];
    __shared__ __align__(16) float qk[D_];
    __shared__ int   list[N_];
    __shared__ int   lcnt;

    if (tid == 0) lcnt = 0;
    if (wave == 0) merge20(wsu, wsi, r, lane, topg);
    if (tid >= 64 && tid < 64 + D_ / 4)
        ((float4*)qk)[tid - 64] = ((const float4*)(qkws + (size_t)r * QKP))[tid - 64];
    __syncthreads();

    for (int i = tid; i < N_; i += NTG)
        nid[i] = nbt[topg[i >> 5] * G_ + (i & 31)];
    __syncthreads();

    for (int i = tid; i < N_; i += NTG) {
        int sv = nid[i];
        if (sv >= lo && sv < hi) { int p = atomicAdd(&lcnt, 1); list[p] = i; }
    }
    __syncthreads();
    const int c2 = lcnt;

    const float ISC = 0.08164965809277260327f;   // 1/sqrt(150)
    const float4* q4 = (const float4*)qk;
    for (int s = tid; s < 8 * c2; s += NTG) {
        int g = s >> 3, h = s & 7;
        int n = list[g];
        const float4* sc4 = (const float4*)(SC + (size_t)nid[n] * D_);
        int c0 = h * 9;
        float acc = 0.f;
        #pragma unroll
        for (int cc = 0; cc < 9; ++cc) {
            float4 a = sc4[c0 + cc];
            float4 bq = q4[c0 + cc];
            acc += a.x * bq.x + a.y * bq.y + a.z * bq.z + a.w * bq.w;
        }
        if (h < 3) {
            float4 a = sc4[72 + h];
            float4 bq = q4[72 + h];
            acc += a.x * bq.x + a.y * bq.y + a.z * bq.z + a.w * bq.w;
        }
        acc += __shfl_xor(acc, 1, 64);
        acc += __shfl_xor(acc, 2, 64);
        acc += __shfl_xor(acc, 4, 64);
        if (h == 0) logws[(size_t)r * N_ + n] = acc * ISC;
    }
}

// == Kernel 3: merge + softmax + last-write-wins dup-kill + scatter ===========
__global__ __launch_bounds__(NTF) void finalize_kernel(
    const float* __restrict__ logws, const int* __restrict__ nbt,
    const unsigned* __restrict__ wsu, const int* __restrict__ wsi,
    float* __restrict__ out)
{
    const int row = blockIdx.x, tid = threadIdx.x;
    const int lane = tid & 63, wave = tid >> 6;
    __shared__ int   topg[K_];
    __shared__ float lg[N_];
    __shared__ int   nid[N_];
    __shared__ int   kills[N_];
    __shared__ float redA[6], redB[6];
    float* outrow = out + (size_t)row * S_;

    if (wave == 0) merge20(wsu, wsi, row, lane, topg);
    __syncthreads();
    if (tid < N_) {
        nid[tid] = nbt[topg[tid >> 5] * G_ + (tid & 31)];
        lg[tid]  = logws[(size_t)row * N_ + tid];
        kills[tid] = 0;
    }
    __syncthreads();

    float v = (tid < N_) ? lg[tid] : -INFINITY;
    float m = v;
    #pragma unroll
    for (int off = 32; off; off >>= 1) m = fmaxf(m, __shfl_xor(m, off, 64));
    if (lane == 0) redA[wave] = m;
    __syncthreads();
    m = redA[0];
    #pragma unroll
    for (int w = 1; w < 6; ++w) m = fmaxf(m, redA[w]);

    float ss = (tid < N_) ? expf(v - m) : 0.f;
    #pragma unroll
    for (int off = 32; off; off >>= 1) ss += __shfl_xor(ss, off, 64);
    if (lane == 0) redB[wave] = ss;
    __syncthreads();
    float tot = redB[0];
    #pragma unroll
    for (int w = 1; w < 6; ++w) tot += redB[w];
    float lsum = logf(tot);

    for (int s = tid; s < 4 * N_; s += NTF) {
        int n = s >> 2, cix = s & 3;
        int sidx = nid[n];
        int clo = cix * 80;
        int lo2 = (n + 1 > clo) ? n + 1 : clo;
        int hi2 = clo + 80;
        bool mt = false;
        #pragma unroll 4
        for (int n2 = lo2; n2 < hi2; ++n2) mt |= (nid[n2] == sidx);
        if (mt) kills[n] = 1;
    }
    __syncthreads();

    if (tid < N_ && !kills[tid]) outrow[nid[tid]] = (v - m) - lsum;
}

// ================= Fallback: fused single kernel (needs no ws) ===============
#define NWS 16
#define NTS 1024
__device__ __forceinline__ bool better(float av, int ai, float bv, int bi) {
    return (av > bv) || (av == bv && ai < bi);
}
__global__ __launch_bounds__(NTS, 4) void selfatt_fused(
    const float* __restrict__ pred, const float* __restrict__ lc,
    const float* __restrict__ SC, const float* __restrict__ Wq,
    const float* __restrict__ Wk, const int* __restrict__ nbt,
    float* __restrict__ out)
{
    const int row = blockIdx.x, tid = threadIdx.x;
    const int lane = tid & 63, wave = tid >> 6;
    __shared__ float wcv[NWS * K_];
    __shared__ int   wci[NWS * K_];
    __shared__ int   topg[K_];
    __shared__ float lcs[D_];
    __shared__ float qs[DQKV_];
    __shared__ __align__(16) float qks[D_];
    __shared__ int   nidx[N_];
    __shared__ float lg[N_];
    __shared__ int   kills[N_];
    __shared__ float redA[NWS], redB[NWS];
    float* outrow = out + (size_t)row * S_;
    const float FILL = -18.420680743952367f;
    {
        float4 f4 = make_float4(FILL, FILL, FILL, FILL);
        float4* o4 = (float4*)outrow;
        #pragma unroll
        for (int k = 0; k < 7; ++k) { int i = tid + k * NTS; if (i < S4) o4[i] = f4; }
    }
    float tv[K_]; int ti[K_];
    #pragma unroll
    for (int s = 0; s < K_; ++s) { tv[s] = -INFINITY; ti[s] = 0x7fffffff; }
    {
        const float4* p4 = (const float4*)(pred + (size_t)row * V_);
        const float4 NEG = make_float4(-INFINITY, -INFINITY, -INFINITY, -INFINITY);
        float4 a[8]; int ib[8];
        #pragma unroll
        for (int u = 0; u < 8; ++u) {
            int i = tid + u * NTS;
            a[u]  = (i < V4) ? p4[i] : NEG;
            ib[u] = (i < V4) ? i * 4 : 0x7ffffff0;
        }
        #pragma unroll
        for (int u = 0; u < 8; ++u) {
            float x = a[u].x, y = a[u].y, z = a[u].z, w = a[u].w;
            float m4 = fmaxf(fmaxf(x, y), fmaxf(z, w));
            if (!(m4 < tv[K_-1])) {
                float vals[4] = {x, y, z, w};
                #pragma unroll
                for (int cc = 0; cc < 4; ++cc) {
                    float val = vals[cc];
                    int   idx = ib[u] + cc;
                    if (better(val, idx, tv[K_-1], ti[K_-1])) {
                        tv[K_-1] = val; ti[K_-1] = idx;
                        #pragma unroll
                        for (int s = K_-1; s > 0; --s) {
                            if (better(tv[s], ti[s], tv[s-1], ti[s-1])) {
                                float fx = tv[s]; tv[s] = tv[s-1]; tv[s-1] = fx;
                                int   iy = ti[s]; ti[s] = ti[s-1]; ti[s-1] = iy;
                            }
                        }
                    }
                }
            }
        }
    }
    for (int p = 0; p < K_; ++p) {
        float bv = tv[0]; int bi = ti[0];
        #pragma unroll
        for (int s = 1; s < K_; ++s)
            if (better(tv[s], ti[s], bv, bi)) { bv = tv[s]; bi = ti[s]; }
        #pragma unroll
        for (int off = 32; off; off >>= 1) {
            float ov = __shfl_xor(bv, off, 64);
            int   oi = __shfl_xor(bi, off, 64);
            if (better(ov, oi, bv, bi)) { bv = ov; bi = oi; }
        }
        if (lane == 0) { wcv[wave * K_ + p] = bv; wci[wave * K_ + p] = bi; }
        #pragma unroll
        for (int s = 0; s < K_; ++s)
            if (ti[s] == bi) tv[s] = -INFINITY;
    }
    __syncthreads();
    if (wave == 0) {
        float c0v = wcv[lane],      c1v = wcv[64 + lane];
        int   c0i = wci[lane],      c1i = wci[64 + lane];
        float c2v = (lane < 32) ? wcv[128 + lane] : -INFINITY;
        int   c2i = (lane < 32) ? wci[128 + lane] : 0x7fffffff;
        for (int p = 0; p < K_; ++p) {
            float bv = c0v; int bi = c0i;
            if (better(c1v, c1i, bv, bi)) { bv = c1v; bi = c1i; }
            if (better(c2v, c2i, bv, bi)) { bv = c2v; bi = c2i; }
            #pragma unroll
            for (int off = 32; off; off >>= 1) {
                float ov = __shfl_xor(bv, off, 64);
                int   oi = __shfl_xor(bi, off, 64);
                if (better(ov, oi, bv, bi)) { bv = ov; bi = oi; }
            }
            if (lane == 0) topg[p] = bi;
            if (c0i == bi) c0v = -INFINITY;
            if (c1i == bi) c1v = -INFINITY;
            if (c2i == bi) c2v = -INFINITY;
        }
    }
    __syncthreads();
    if (tid < N_) { int g = topg[tid >> 5]; nidx[tid] = nbt[g * G_ + (tid & 31)]; }
    else if (tid < 2 * N_) kills[tid - N_] = 0;
    else if (tid >= 640 && tid < 640 + D_) lcs[tid - 640] = lc[(size_t)row * D_ + (tid - 640)];
    __syncthreads();
    if (tid < 600) {
        int j = tid >> 2, h = tid & 3;
        int d0 = h * 75;
        const float* wp = Wq + (size_t)d0 * DQKV_ + j;
        float acc = 0.f;
        #pragma unroll 5
        for (int dd = 0; dd < 75; ++dd) acc += lcs[d0 + dd] * wp[(size_t)dd * DQKV_];
        acc += __shfl_xor(acc, 1, 64);
        acc += __shfl_xor(acc, 2, 64);
        if (h == 0) qs[j] = acc;
    } else {
        int t0 = tid - 600;
        for (int s = t0; s < 4 * N_; s += 424) {
            int n = s >> 2, cc = s & 3;
            int sidx = nidx[n];
            int clo = cc * 80;
            int lo = (n + 1 > clo) ? n + 1 : clo;
            int hi = clo + 80;
            bool mt = false;
            #pragma unroll 4
            for (int n2 = lo; n2 < hi; ++n2) mt |= (nidx[n2] == sidx);
            if (mt) kills[n] = 1;
        }
    }
    __syncthreads();
    if (tid < 600) {
        int d = tid >> 1, h = tid & 1;
        int j0 = h * 75;
        const float* wrow = Wk + (size_t)d * DQKV_ + j0;
        float acc = 0.f;
        #pragma unroll 5
        for (int jj = 0; jj < 75; ++jj) acc += wrow[jj] * qs[j0 + jj];
        acc += __shfl_xor(acc, 1, 64);
        if (h == 0) qks[d] = acc;
    }
    __syncthreads();
    const float ISC = 0.08164965809277260327f;
    const float4* q4 = (const float4*)qks;
    for (int s = tid; s < 8 * N_; s += NTS) {
        int n = s >> 3, h = s & 7;
        const float4* sc4 = (const float4*)(SC + (size_t)nidx[n] * D_);
        int c0 = h * 9;
        float acc = 0.f;
        #pragma unroll
        for (int cc = 0; cc < 9; ++cc) {
            float4 a = sc4[c0 + cc];
            float4 b = q4[c0 + cc];
            acc += a.x * b.x + a.y * b.y + a.z * b.z + a.w * b.w;
        }
        if (h < 3) {
            float4 a = sc4[72 + h];
            float4 b = q4[72 + h];
            acc += a.x * b.x + a.y * b.y + a.z * b.z + a.w * b.w;
        }
        acc += __shfl_xor(acc, 1, 64);
        acc += __shfl_xor(acc, 2, 64);
        acc += __shfl_xor(acc, 4, 64);
        if (h == 0) lg[n] = acc * ISC;
    }
    __syncthreads();
    float v = (tid < N_) ? lg[tid] : -INFINITY;
    float m = v;
    #pragma unroll
    for (int off = 32; off; off >>= 1) m = fmaxf(m, __shfl_xor(m, off, 64));
    if (lane == 0) redA[wave] = m;
    __syncthreads();
    m = redA[0];
    #pragma unroll
    for (int w = 1; w < NWS; ++w) m = fmaxf(m, redA[w]);
    float e = (tid < N_) ? expf(v - m) : 0.f;
    float ss = e;
    #pragma unroll
    for (int off = 32; off; off >>= 1) ss += __shfl_xor(ss, off, 64);
    if (lane == 0) redB[wave] = ss;
    __syncthreads();
    float tot = redB[0];
    #pragma unroll
    for (int w = 1; w < NWS; ++w) tot += redB[w];
    float lsum = logf(tot);
    if (tid < N_ && !kills[tid]) outrow[nidx[tid]] = (v - m) - lsum;
}

extern "C" void kernel_launch(void* const* d_in, const int* in_sizes, int n_in,
                              void* d_out, int out_size, void* d_ws, size_t ws_size,
                              hipStream_t stream) {
    const float* pred = (const float*)d_in[0];
    const float* lc   = (const float*)d_in[1];
    const float* SC   = (const float*)d_in[2];
    const float* Wq   = (const float*)d_in[3];
    const float* Wk   = (const float*)d_in[4];
    const int*   nbt  = (const int*)d_in[5];
    float* out = (float*)d_out;

    const int nrows = T_ * B_;
    const size_t nQK = (size_t)nrows * QKP;            // floats
    const size_t nLG = (size_t)nrows * N_;             // floats
    const size_t nCD = (size_t)nrows * 2 * K_;         // (u,i) candidate pairs
    const size_t need = (nQK + nLG) * sizeof(float) + nCD * (sizeof(int) + 4);

    if (ws_size >= need) {
        float*    qkws  = (float*)d_ws;
        float*    logws = qkws + nQK;
        unsigned* wsu   = (unsigned*)(logws + nLG);
        int*      wsi   = (int*)(wsu + nCD);
        stage1_kernel<<<dim3(NSCAN + NQK), dim3(NT1), 0, stream>>>(
            pred, lc, Wq, Wk, out, wsu, wsi, qkws);
        gather_kernel<<<dim3(nrows * 8), dim3(NTG), 0, stream>>>(
            SC, qkws, nbt, wsu, wsi, logws);
        finalize_kernel<<<dim3(nrows), dim3(NTF), 0, stream>>>(
            logws, nbt, wsu, wsi, out);
    } else {
        selfatt_fused<<<dim3(nrows), dim3(NTS), 0, stream>>>(
            pred, lc, SC, Wq, Wk, nbt, out);
    }
}

// Round 22
// 104.985 us; speedup vs baseline: 1.8369x; 1.1069x over previous
//
#include <hip/hip_runtime.h>
#include <math.h>

#define T_ 32
#define B_ 16
#define V_ 30000
#define V4 7500
#define D_ 300
#define DQKV_ 150
#define K_ 10
#define G_ 32
#define N_ 320                // K*G
#define S_ 25000
#define S4 6250
#define SLICE 3125            // S/8: SC row-range per XCD (3.75 MB = one L2)
#define QKP 304               // qk ws row stride (300 -> 304, 16B aligned)
#define NTS 1024              // stage1 threads
#define NTG 256               // gather threads
#define NTF 1024              // finalize threads (carries the fill now)
#define LCAP 4096             // candidate list capacity (expect ~680 for N(0,1))
#define UTH 0xC0000000u       // u-map(2.0f): accept x >= 2.0

__device__ __forceinline__ unsigned umap(float f) {
    unsigned b = __float_as_uint(f);
    unsigned mask = (unsigned)(((int)b) >> 31);      // 0xFFFFFFFF if negative
    return b ^ (mask | 0x80000000u);                 // ascending uint == ascending float
}
__device__ __forceinline__ bool better_u(unsigned au, int ai, unsigned bu, int bi) {
    return (au > bu) || (au == bu && ai < bi);       // higher val, ties -> lower idx
}

// == Kernel 1 (block-specialized, PURE-READ scan — fill moved to finalize):
//    blocks [0,512):    ballot-collect + 16-wave parallel top-10 -> wstop
//    blocks [512,1024): q = lc@Wq, qk = Wk@q -> qkws
__global__ __launch_bounds__(NTS, 2) void stage1_kernel(
    const float* __restrict__ pred, const float* __restrict__ lc,
    const float* __restrict__ Wq, const float* __restrict__ Wk,
    int* __restrict__ wstop, float* __restrict__ qkws)
{
    const int b = blockIdx.x, tid = threadIdx.x;
    const int lane = tid & 63, wave = tid >> 6;
    __shared__ unsigned lu[LCAP];          // 16 KB candidate u-keys
    __shared__ int      li[LCAP];          // 16 KB candidate indices
    __shared__ int      cnt;
    __shared__ unsigned wcv[16 * K_];
    __shared__ int      wci[16 * K_];
    __shared__ __align__(16) float lcs[D_];
    __shared__ float    qpart[2][DQKV_];

    if (b >= T_ * B_) {
        // ---------------- qk path ----------------
        const int row = b - T_ * B_;
        if (tid < D_ / 4)
            ((float4*)lcs)[tid] = ((const float4*)(lc + (size_t)row * D_))[tid];
        __syncthreads();

        // q-partials: thread-per-(half,j); Wq loads coalesced in j
        if (tid < 2 * DQKV_) {
            int h = tid / DQKV_;
            int j = tid - h * DQKV_;
            int d0 = h * 150;
            const float* wp = Wq + (size_t)d0 * DQKV_ + j;
            float a0 = 0.f, a1 = 0.f;
            #pragma unroll 5
            for (int dd = 0; dd < 150; dd += 2) {
                a0 += lcs[d0 + dd]     * wp[(size_t)dd * DQKV_];
                a1 += lcs[d0 + dd + 1] * wp[(size_t)(dd + 1) * DQKV_];
            }
            qpart[h][j] = a0 + a1;
        }
        __syncthreads();

        // qk[d] = Wk[d,:] . q — wave per d-row (16 waves), coalesced + shfl
        float qv0 = qpart[0][lane] + qpart[1][lane];
        float qv1 = qpart[0][64 + lane] + qpart[1][64 + lane];
        float qv2 = (lane < 22) ? (qpart[0][128 + lane] + qpart[1][128 + lane]) : 0.f;
        for (int d = wave; d < D_; d += 16) {
            const float* wr = Wk + (size_t)d * DQKV_;
            float w0 = wr[lane];
            float w1 = wr[64 + lane];
            float w2 = (lane < 22) ? wr[128 + lane] : 0.f;
            float p = w0 * qv0 + w1 * qv1 + w2 * qv2;
            #pragma unroll
            for (int off = 32; off; off >>= 1) p += __shfl_xor(p, off, 64);
            if (lane == 0) qkws[(size_t)row * QKP + d] = p;
        }
        return;
    }

    // ---------------- scan path (NO fill — pure pred read) ----------------
    const int row = b;
    if (tid == 0) cnt = 0;
    __syncthreads();

    {
        const float4* p4 = (const float4*)(pred + (size_t)row * V_);
        const float4 NEG = make_float4(-INFINITY, -INFINITY, -INFINITY, -INFINITY);
        float4 a[8]; int ib[8]; bool okf[8];
        #pragma unroll
        for (int u = 0; u < 8; ++u) {
            int i = tid + u * NTS;
            okf[u] = i < V4;
            a[u]  = okf[u] ? p4[i] : NEG;
            ib[u] = i * 4;
        }
        const unsigned long long lmask = (lane == 63) ? 0x7fffffffffffffffull
                                                      : ((1ull << lane) - 1ull);
        #pragma unroll
        for (int u = 0; u < 8; ++u) {
            float vals[4] = {a[u].x, a[u].y, a[u].z, a[u].w};
            #pragma unroll
            for (int c = 0; c < 4; ++c) {
                unsigned uu = umap(vals[c]);
                bool has = okf[u] && (uu >= UTH);
                unsigned long long mask = __ballot(has);
                if (mask) {
                    int bs = 0;
                    if (lane == 0) bs = atomicAdd(&cnt, (int)__popcll(mask));
                    bs = __shfl(bs, 0, 64);
                    if (has) {
                        int p = bs + (int)__popcll(mask & lmask);
                        if (p < LCAP) { lu[p] = uu; li[p] = ib[u] + c; }
                    }
                }
            }
        }
    }
    __syncthreads();
    const int c = cnt;
    const bool mainpath = (c >= K_ && c <= LCAP);

    if (mainpath) {
        // 16-wave parallel select: each wave top-10 of its strided subset
        unsigned cu[4]; int cix[4];
        #pragma unroll
        for (int k = 0; k < 4; ++k) {
            int s = wave * 64 + lane + k * NTS;
            bool ok = s < c;
            cu[k]  = ok ? lu[s] : 0u;
            cix[k] = ok ? li[s] : 0x7fffffff;
        }
        for (int p = 0; p < K_; ++p) {
            unsigned bu = cu[0]; int bi = cix[0];
            #pragma unroll
            for (int k = 1; k < 4; ++k)
                if (better_u(cu[k], cix[k], bu, bi)) { bu = cu[k]; bi = cix[k]; }
            #pragma unroll
            for (int off = 32; off; off >>= 1) {
                unsigned ou = __shfl_xor(bu, off, 64);
                int      oi = __shfl_xor(bi, off, 64);
                if (better_u(ou, oi, bu, bi)) { bu = ou; bi = oi; }
            }
            if (lane == 0) { wcv[wave * K_ + p] = bu; wci[wave * K_ + p] = bi; }
            #pragma unroll
            for (int k = 0; k < 4; ++k)
                if (cix[k] == bi) cu[k] = 0u;
        }
        __syncthreads();

        // wave 0 merges the 160 wave-winners
        if (wave == 0) {
            unsigned c0u = wcv[lane],      c1u = wcv[64 + lane];
            int      c0i = wci[lane],      c1i = wci[64 + lane];
            unsigned c2u = (lane < 32) ? wcv[128 + lane] : 0u;
            int      c2i = (lane < 32) ? wci[128 + lane] : 0x7fffffff;
            for (int p = 0; p < K_; ++p) {
                unsigned bu = c0u; int bi = c0i;
                if (better_u(c1u, c1i, bu, bi)) { bu = c1u; bi = c1i; }
                if (better_u(c2u, c2i, bu, bi)) { bu = c2u; bi = c2i; }
                #pragma unroll
                for (int off = 32; off; off >>= 1) {
                    unsigned ou = __shfl_xor(bu, off, 64);
                    int      oi = __shfl_xor(bi, off, 64);
                    if (better_u(ou, oi, bu, bi)) { bu = ou; bi = oi; }
                }
                if (lane == 0) wstop[row * K_ + p] = bi;
                if (c0i == bi) c0u = 0u;
                if (c1i == bi) c1u = 0u;
                if (c2i == bi) c2u = 0u;
            }
        }
    } else {
        // exact fallback (never triggers for N(0,1)): wave0 re-scans row
        if (wave == 0) {
            unsigned tu[K_]; int tix[K_];
            #pragma unroll
            for (int s = 0; s < K_; ++s) { tu[s] = 0; tix[s] = 0x7fffffff; }
            const float* prow = pred + (size_t)row * V_;
            for (int i = lane; i < V_; i += 64) {
                unsigned u = umap(prow[i]);
                if (better_u(u, i, tu[K_-1], tix[K_-1])) {
                    tu[K_-1] = u; tix[K_-1] = i;
                    #pragma unroll
                    for (int s = K_-1; s > 0; --s)
                        if (better_u(tu[s], tix[s], tu[s-1], tix[s-1])) {
                            unsigned a = tu[s]; tu[s] = tu[s-1]; tu[s-1] = a;
                            int b2 = tix[s]; tix[s] = tix[s-1]; tix[s-1] = b2;
                        }
                }
            }
            for (int p = 0; p < K_; ++p) {
                unsigned bu = tu[0]; int bi = tix[0];
                #pragma unroll
                for (int s = 1; s < K_; ++s)
                    if (better_u(tu[s], tix[s], bu, bi)) { bu = tu[s]; bi = tix[s]; }
                #pragma unroll
                for (int off = 32; off; off >>= 1) {
                    unsigned ou = __shfl_xor(bu, off, 64);
                    int      oi = __shfl_xor(bi, off, 64);
                    if (better_u(ou, oi, bu, bi)) { bu = ou; bi = oi; }
                }
                if (lane == 0) wstop[row * K_ + p] = bi;
                #pragma unroll
                for (int s = 0; s < K_; ++s)
                    if (tix[s] == bi) tu[s] = 0;
            }
        }
    }
}

// == Kernel 2: XCD-local gather (computes nidx from wstop+nbt itself) ========
__global__ __launch_bounds__(NTG) void gather_kernel(
    const float* __restrict__ SC, const float* __restrict__ qkws,
    const int* __restrict__ nbt, const int* __restrict__ wstop,
    float* __restrict__ logws)
{
    const int r = blockIdx.x >> 3;
    const int ch = blockIdx.x & 7;
    const int lo = ch * SLICE, hi = lo + SLICE;
    const int tid = threadIdx.x;
    __shared__ int   topg[K_];
    __shared__ int   nid[N_];
    __shared__ __align__(16) float qk[D_];
    __shared__ int   list[N_];
    __shared__ int   lcnt;

    if (tid == 0) lcnt = 0;
    if (tid < K_) topg[tid] = wstop[r * K_ + tid];
    if (tid >= 64 && tid < 64 + D_ / 4)
        ((float4*)qk)[tid - 64] = ((const float4*)(qkws + (size_t)r * QKP))[tid - 64];
    __syncthreads();

    for (int i = tid; i < N_; i += NTG)
        nid[i] = nbt[topg[i >> 5] * G_ + (i & 31)];
    __syncthreads();

    for (int i = tid; i < N_; i += NTG) {
        int sv = nid[i];
        if (sv >= lo && sv < hi) { int p = atomicAdd(&lcnt, 1); list[p] = i; }
    }
    __syncthreads();
    const int c2 = lcnt;

    const float ISC = 0.08164965809277260327f;   // 1/sqrt(150)
    const float4* q4 = (const float4*)qk;
    for (int s = tid; s < 8 * c2; s += NTG) {
        int g = s >> 3, h = s & 7;
        int n = list[g];
        const float4* sc4 = (const float4*)(SC + (size_t)nid[n] * D_);
        int c0 = h * 9;
        float acc = 0.f;
        #pragma unroll
        for (int cc = 0; cc < 9; ++cc) {
            float4 a = sc4[c0 + cc];
            float4 bq = q4[c0 + cc];
            acc += a.x * bq.x + a.y * bq.y + a.z * bq.z + a.w * bq.w;
        }
        if (h < 3) {
            float4 a = sc4[72 + h];
            float4 bq = q4[72 + h];
            acc += a.x * bq.x + a.y * bq.y + a.z * bq.z + a.w * bq.w;
        }
        acc += __shfl_xor(acc, 1, 64);
        acc += __shfl_xor(acc, 2, 64);
        acc += __shfl_xor(acc, 4, 64);
        if (h == 0) logws[(size_t)r * N_ + n] = acc * ISC;
    }
}

// == Kernel 3: FILL + softmax + last-write-wins dup-kill + scatter ============
__global__ __launch_bounds__(NTF) void finalize_kernel(
    const float* __restrict__ logws, const int* __restrict__ nbt,
    const int* __restrict__ wstop, float* __restrict__ out)
{
    const int row = blockIdx.x, tid = threadIdx.x;
    const int lane = tid & 63, wave = tid >> 6;
    __shared__ int   topg[K_];
    __shared__ float lg[N_];
    __shared__ int   nid[N_];
    __shared__ int   kills[N_];
    __shared__ float redA[16], redB[16];
    float* outrow = out + (size_t)row * S_;

    // fill whole row with log(1e-8); drained before scatter by the barriers
    const float FILL = -18.420680743952367f;
    {
        float4 f4 = make_float4(FILL, FILL, FILL, FILL);
        float4* o4 = (float4*)outrow;
        #pragma unroll
        for (int k = 0; k < 7; ++k) { int i = tid + k * NTF; if (i < S4) o4[i] = f4; }
    }

    if (tid < K_) topg[tid] = wstop[row * K_ + tid];
    __syncthreads();
    if (tid < N_) {
        nid[tid] = nbt[topg[tid >> 5] * G_ + (tid & 31)];
        lg[tid]  = logws[(size_t)row * N_ + tid];
        kills[tid] = 0;
    }
    __syncthreads();

    float v = (tid < N_) ? lg[tid] : -INFINITY;
    float m = v;
    #pragma unroll
    for (int off = 32; off; off >>= 1) m = fmaxf(m, __shfl_xor(m, off, 64));
    if (lane == 0) redA[wave] = m;
    __syncthreads();
    m = redA[0];
    #pragma unroll
    for (int w = 1; w < 16; ++w) m = fmaxf(m, redA[w]);

    float ss = (tid < N_) ? expf(v - m) : 0.f;
    #pragma unroll
    for (int off = 32; off; off >>= 1) ss += __shfl_xor(ss, off, 64);
    if (lane == 0) redB[wave] = ss;
    __syncthreads();
    float tot = redB[0];
    #pragma unroll
    for (int w = 1; w < 16; ++w) tot += redB[w];
    float lsum = logf(tot);

    for (int s = tid; s < 4 * N_; s += NTF) {
        int n = s >> 2, cix = s & 3;
        int sidx = nid[n];
        int clo = cix * 80;
        int lo2 = (n + 1 > clo) ? n + 1 : clo;
        int hi2 = clo + 80;
        bool mt = false;
        #pragma unroll 4
        for (int n2 = lo2; n2 < hi2; ++n2) mt |= (nid[n2] == sidx);
        if (mt) kills[n] = 1;
    }
    __syncthreads();

    if (tid < N_ && !kills[tid]) outrow[nid[tid]] = (v - m) - lsum;
}

// ================= Fallback: fused single kernel (needs no ws) ===============
#define NWS 16
__device__ __forceinline__ bool better(float av, int ai, float bv, int bi) {
    return (av > bv) || (av == bv && ai < bi);
}
__global__ __launch_bounds__(NTS, 4) void selfatt_fused(
    const float* __restrict__ pred, const float* __restrict__ lc,
    const float* __restrict__ SC, const float* __restrict__ Wq,
    const float* __restrict__ Wk, const int* __restrict__ nbt,
    float* __restrict__ out)
{
    const int row = blockIdx.x, tid = threadIdx.x;
    const int lane = tid & 63, wave = tid >> 6;
    __shared__ float wcv[NWS * K_];
    __shared__ int   wci[NWS * K_];
    __shared__ int   topg[K_];
    __shared__ float lcs[D_];
    __shared__ float qs[DQKV_];
    __shared__ __align__(16) float qks[D_];
    __shared__ int   nidx[N_];
    __shared__ float lg[N_];
    __shared__ int   kills[N_];
    __shared__ float redA[NWS], redB[NWS];
    float* outrow = out + (size_t)row * S_;
    const float FILL = -18.420680743952367f;
    {
        float4 f4 = make_float4(FILL, FILL, FILL, FILL);
        float4* o4 = (float4*)outrow;
        #pragma unroll
        for (int k = 0; k < 7; ++k) { int i = tid + k * NTS; if (i < S4) o4[i] = f4; }
    }
    float tv[K_]; int ti[K_];
    #pragma unroll
    for (int s = 0; s < K_; ++s) { tv[s] = -INFINITY; ti[s] = 0x7fffffff; }
    {
        const float4* p4 = (const float4*)(pred + (size_t)row * V_);
        const float4 NEG = make_float4(-INFINITY, -INFINITY, -INFINITY, -INFINITY);
        float4 a[8]; int ib[8];
        #pragma unroll
        for (int u = 0; u < 8; ++u) {
            int i = tid + u * NTS;
            a[u]  = (i < V4) ? p4[i] : NEG;
            ib[u] = (i < V4) ? i * 4 : 0x7ffffff0;
        }
        #pragma unroll
        for (int u = 0; u < 8; ++u) {
            float x = a[u].x, y = a[u].y, z = a[u].z, w = a[u].w;
            float m4 = fmaxf(fmaxf(x, y), fmaxf(z, w));
            if (!(m4 < tv[K_-1])) {
                float vals[4] = {x, y, z, w};
                #pragma unroll
                for (int cc = 0; cc < 4; ++cc) {
                    float val = vals[cc];
                    int   idx = ib[u] + cc;
                    if (better(val, idx, tv[K_-1], ti[K_-1])) {
                        tv[K_-1] = val; ti[K_-1] = idx;
                        #pragma unroll
                        for (int s = K_-1; s > 0; --s) {
                            if (better(tv[s], ti[s], tv[s-1], ti[s-1])) {
                                float fx = tv[s]; tv[s] = tv[s-1]; tv[s-1] = fx;
                                int   iy = ti[s]; ti[s] = ti[s-1]; ti[s-1] = iy;
                            }
                        }
                    }
                }
            }
        }
    }
    for (int p = 0; p < K_; ++p) {
        float bv = tv[0]; int bi = ti[0];
        #pragma unroll
        for (int s = 1; s < K_; ++s)
            if (better(tv[s], ti[s], bv, bi)) { bv = tv[s]; bi = ti[s]; }
        #pragma unroll
        for (int off = 32; off; off >>= 1) {
            float ov = __shfl_xor(bv, off, 64);
            int   oi = __shfl_xor(bi, off, 64);
            if (better(ov, oi, bv, bi)) { bv = ov; bi = oi; }
        }
        if (lane == 0) { wcv[wave * K_ + p] = bv; wci[wave * K_ + p] = bi; }
        #pragma unroll
        for (int s = 0; s < K_; ++s)
            if (ti[s] == bi) tv[s] = -INFINITY;
    }
    __syncthreads();
    if (wave == 0) {
        float c0v = wcv[lane],      c1v = wcv[64 + lane];
        int   c0i = wci[lane],      c1i = wci[64 + lane];
        float c2v = (lane < 32) ? wcv[128 + lane] : -INFINITY;
        int   c2i = (lane < 32) ? wci[128 + lane] : 0x7fffffff;
        for (int p = 0; p < K_; ++p) {
            float bv = c0v; int bi = c0i;
            if (better(c1v, c1i, bv, bi)) { bv = c1v; bi = c1i; }
            if (better(c2v, c2i, bv, bi)) { bv = c2v; bi = c2i; }
            #pragma unroll
            for (int off = 32; off; off >>= 1) {
                float ov = __shfl_xor(bv, off, 64);
                int   oi = __shfl_xor(bi, off, 64);
                if (better(ov, oi, bv, bi)) { bv = ov; bi = oi; }
            }
            if (lane == 0) topg[p] = bi;
            if (c0i == bi) c0v = -INFINITY;
            if (c1i == bi) c1v = -INFINITY;
            if (c2i == bi) c2v = -INFINITY;
        }
    }
    __syncthreads();
    if (tid < N_) { int g = topg[tid >> 5]; nidx[tid] = nbt[g * G_ + (tid & 31)]; }
    else if (tid < 2 * N_) kills[tid - N_] = 0;
    else if (tid >= 640 && tid < 640 + D_) lcs[tid - 640] = lc[(size_t)row * D_ + (tid - 640)];
    __syncthreads();
    if (tid < 600) {
        int j = tid >> 2, h = tid & 3;
        int d0 = h * 75;
        const float* wp = Wq + (size_t)d0 * DQKV_ + j;
        float acc = 0.f;
        #pragma unroll 5
        for (int dd = 0; dd < 75; ++dd) acc += lcs[d0 + dd] * wp[(size_t)dd * DQKV_];
        acc += __shfl_xor(acc, 1, 64);
        acc += __shfl_xor(acc, 2, 64);
        if (h == 0) qs[j] = acc;
    } else {
        int t0 = tid - 600;
        for (int s = t0; s < 4 * N_; s += 424) {
            int n = s >> 2, cc = s & 3;
            int sidx = nidx[n];
            int clo = cc * 80;
            int lo = (n + 1 > clo) ? n + 1 : clo;
            int hi = clo + 80;
            bool mt = false;
            #pragma unroll 4
            for (int n2 = lo; n2 < hi; ++n2) mt |= (nidx[n2] == sidx);
            if (mt) kills[n] = 1;
        }
    }
    __syncthreads();
    if (tid < 600) {
        int d = tid >> 1, h = tid & 1;
        int j0 = h * 75;
        const float* wrow = Wk + (size_t)d * DQKV_ + j0;
        float acc = 0.f;
        #pragma unroll 5
        for (int jj = 0; jj < 75; ++jj) acc += wrow[jj] * qs[j0 + jj];
        acc += __shfl_xor(acc, 1, 64);
        if (h == 0) qks[d] = acc;
    }
    __syncthreads();
    const float ISC = 0.08164965809277260327f;
    const float4* q4 = (const float4*)qks;
    for (int s = tid; s < 8 * N_; s += NTS) {
        int n = s >> 3, h = s & 7;
        const float4* sc4 = (const float4*)(SC + (size_t)nidx[n] * D_);
        int c0 = h * 9;
        float acc = 0.f;
        #pragma unroll
        for (int cc = 0; cc < 9; ++cc) {
            float4 a = sc4[c0 + cc];
            float4 b = q4[c0 + cc];
            acc += a.x * b.x + a.y * b.y + a.z * b.z + a.w * b.w;
        }
        if (h < 3) {
            float4 a = sc4[72 + h];
            float4 b = q4[72 + h];
            acc += a.x * b.x + a.y * b.y + a.z * b.z + a.w * b.w;
        }
        acc += __shfl_xor(acc, 1, 64);
        acc += __shfl_xor(acc, 2, 64);
        acc += __shfl_xor(acc, 4, 64);
        if (h == 0) lg[n] = acc * ISC;
    }
    __syncthreads();
    float v = (tid < N_) ? lg[tid] : -INFINITY;
    float m = v;
    #pragma unroll
    for (int off = 32; off; off >>= 1) m = fmaxf(m, __shfl_xor(m, off, 64));
    if (lane == 0) redA[wave] = m;
    __syncthreads();
    m = redA[0];
    #pragma unroll
    for (int w = 1; w < NWS; ++w) m = fmaxf(m, redA[w]);
    float e = (tid < N_) ? expf(v - m) : 0.f;
    float ss = e;
    #pragma unroll
    for (int off = 32; off; off >>= 1) ss += __shfl_xor(ss, off, 64);
    if (lane == 0) redB[wave] = ss;
    __syncthreads();
    float tot = redB[0];
    #pragma unroll
    for (int w = 1; w < NWS; ++w) tot += redB[w];
    float lsum = logf(tot);
    if (tid < N_ && !kills[tid]) outrow[nidx[tid]] = (v - m) - lsum;
}

extern "C" void kernel_launch(void* const* d_in, const int* in_sizes, int n_in,
                              void* d_out, int out_size, void* d_ws, size_t ws_size,
                              hipStream_t stream) {
    const float* pred = (const float*)d_in[0];
    const float* lc   = (const float*)d_in[1];
    const float* SC   = (const float*)d_in[2];
    const float* Wq   = (const float*)d_in[3];
    const float* Wk   = (const float*)d_in[4];
    const int*   nbt  = (const int*)d_in[5];
    float* out = (float*)d_out;

    const int nrows = T_ * B_;
    const size_t nQK = (size_t)nrows * QKP;            // floats
    const size_t nLG = (size_t)nrows * N_;             // floats
    const size_t nTP = (size_t)nrows * K_;             // ints (wstop)
    const size_t need = (nQK + nLG) * sizeof(float) + nTP * sizeof(int);

    if (ws_size >= need) {
        float* qkws  = (float*)d_ws;
        float* logws = qkws + nQK;
        int*   wstop = (int*)(logws + nLG);
        stage1_kernel<<<dim3(nrows * 2), dim3(NTS), 0, stream>>>(
            pred, lc, Wq, Wk, wstop, qkws);
        gather_kernel<<<dim3(nrows * 8), dim3(NTG), 0, stream>>>(
            SC, qkws, nbt, wstop, logws);
        finalize_kernel<<<dim3(nrows), dim3(NTF), 0, stream>>>(
            logws, nbt, wstop, out);
    } else {
        selfatt_fused<<<dim3(nrows), dim3(NTS), 0, stream>>>(
            pred, lc, SC, Wq, Wk, nbt, out);
    }
}

// Round 23
// 104.505 us; speedup vs baseline: 1.8453x; 1.0046x over previous
//
#include <hip/hip_runtime.h>
#include <math.h>

#define T_ 32
#define B_ 16
#define V_ 30000
#define V4 7500
#define D_ 300
#define DQKV_ 150
#define K_ 10
#define G_ 32
#define N_ 320                // K*G
#define S_ 25000
#define S4 6250
#define SLICE 3125            // S/8: SC row-range per XCD (3.75 MB = one L2)
#define QKP 304               // qk ws row stride (300 -> 304, 16B aligned)
#define NTS 1024              // stage1 threads
#define NTG 256               // gather threads
#define NTF 384               // finalize threads
#define LCAP 4096             // candidate list capacity (expect ~680 for N(0,1))
#define UTH 0xC0000000u       // u-map(2.0f): accept x >= 2.0

__device__ __forceinline__ unsigned umap(float f) {
    unsigned b = __float_as_uint(f);
    unsigned mask = (unsigned)(((int)b) >> 31);      // 0xFFFFFFFF if negative
    return b ^ (mask | 0x80000000u);                 // ascending uint == ascending float
}
__device__ __forceinline__ bool better_u(unsigned au, int ai, unsigned bu, int bi) {
    return (au > bu) || (au == bu && ai < bi);       // higher val, ties -> lower idx
}

// == Kernel 1 (block-specialized, pure-read scan, ATOMIC-FREE collect):
//    blocks [0,512):    prefix-sum collect + 16-wave parallel top-10 -> wstop
//    blocks [512,1024): q = lc@Wq, qk = Wk@q -> qkws
__global__ __launch_bounds__(NTS, 2) void stage1_kernel(
    const float* __restrict__ pred, const float* __restrict__ lc,
    const float* __restrict__ Wq, const float* __restrict__ Wk,
    int* __restrict__ wstop, float* __restrict__ qkws)
{
    const int b = blockIdx.x, tid = threadIdx.x;
    const int lane = tid & 63, wave = tid >> 6;
    __shared__ unsigned lu[LCAP];          // 16 KB candidate u-keys
    __shared__ int      li[LCAP];          // 16 KB candidate indices
    __shared__ int      wtot[16];
    __shared__ unsigned wcv[16 * K_];
    __shared__ int      wci[16 * K_];
    __shared__ __align__(16) float lcs[D_];
    __shared__ float    qpart[2][DQKV_];

    if (b >= T_ * B_) {
        // ---------------- qk path ----------------
        const int row = b - T_ * B_;
        if (tid < D_ / 4)
            ((float4*)lcs)[tid] = ((const float4*)(lc + (size_t)row * D_))[tid];
        __syncthreads();

        // q-partials: thread-per-(half,j); Wq loads coalesced in j
        if (tid < 2 * DQKV_) {
            int h = tid / DQKV_;
            int j = tid - h * DQKV_;
            int d0 = h * 150;
            const float* wp = Wq + (size_t)d0 * DQKV_ + j;
            float a0 = 0.f, a1 = 0.f;
            #pragma unroll 5
            for (int dd = 0; dd < 150; dd += 2) {
                a0 += lcs[d0 + dd]     * wp[(size_t)dd * DQKV_];
                a1 += lcs[d0 + dd + 1] * wp[(size_t)(dd + 1) * DQKV_];
            }
            qpart[h][j] = a0 + a1;
        }
        __syncthreads();

        // qk[d] = Wk[d,:] . q — wave per d-row (16 waves), coalesced + shfl
        float qv0 = qpart[0][lane] + qpart[1][lane];
        float qv1 = qpart[0][64 + lane] + qpart[1][64 + lane];
        float qv2 = (lane < 22) ? (qpart[0][128 + lane] + qpart[1][128 + lane]) : 0.f;
        for (int d = wave; d < D_; d += 16) {
            const float* wr = Wk + (size_t)d * DQKV_;
            float w0 = wr[lane];
            float w1 = wr[64 + lane];
            float w2 = (lane < 22) ? wr[128 + lane] : 0.f;
            float p = w0 * qv0 + w1 * qv1 + w2 * qv2;
            #pragma unroll
            for (int off = 32; off; off >>= 1) p += __shfl_xor(p, off, 64);
            if (lane == 0) qkws[(size_t)row * QKP + d] = p;
        }
        return;
    }

    // ---------------- scan path (pure read; no atomics) ----------------
    const int row = b;

    // load 8 float4 (32 elements) into registers
    const float4* p4 = (const float4*)(pred + (size_t)row * V_);
    const float4 NEG = make_float4(-INFINITY, -INFINITY, -INFINITY, -INFINITY);
    float4 a[8]; int ib[8]; bool okf[8];
    #pragma unroll
    for (int u = 0; u < 8; ++u) {
        int i = tid + u * NTS;
        okf[u] = i < V4;
        a[u]  = okf[u] ? p4[i] : NEG;
        ib[u] = i * 4;
    }

    // pass A: count accepted (pure VALU)
    int nc = 0;
    #pragma unroll
    for (int u = 0; u < 8; ++u) {
        nc += (okf[u] && umap(a[u].x) >= UTH);
        nc += (okf[u] && umap(a[u].y) >= UTH);
        nc += (okf[u] && umap(a[u].z) >= UTH);
        nc += (okf[u] && umap(a[u].w) >= UTH);
    }

    // wave inclusive scan of nc (6-step shfl_up)
    int incl = nc;
    #pragma unroll
    for (int d = 1; d < 64; d <<= 1) {
        int t = __shfl_up(incl, d, 64);
        if (lane >= d) incl += t;
    }
    if (lane == 63) wtot[wave] = incl;               // wave total
    __syncthreads();

    int wbase = 0, c = 0;
    #pragma unroll
    for (int w = 0; w < 16; ++w) {
        int t = wtot[w];
        if (w < wave) wbase += t;
        c += t;
    }
    int pos = wbase + (incl - nc);                   // exclusive prefix

    // pass B: write accepted elements to exclusive range (no atomics)
    #pragma unroll
    for (int u = 0; u < 8; ++u) {
        float vals[4] = {a[u].x, a[u].y, a[u].z, a[u].w};
        #pragma unroll
        for (int cc = 0; cc < 4; ++cc) {
            unsigned uu = umap(vals[cc]);
            if (okf[u] && uu >= UTH && pos < LCAP) {
                lu[pos] = uu; li[pos] = ib[u] + cc; ++pos;
            }
        }
    }
    __syncthreads();
    const bool mainpath = (c >= K_ && c <= LCAP);

    if (mainpath) {
        // 16-wave parallel select: each wave top-10 of its strided subset
        unsigned cu[4]; int cix[4];
        #pragma unroll
        for (int k = 0; k < 4; ++k) {
            int s = wave * 64 + lane + k * NTS;
            bool ok = s < c;
            cu[k]  = ok ? lu[s] : 0u;
            cix[k] = ok ? li[s] : 0x7fffffff;
        }
        for (int p = 0; p < K_; ++p) {
            unsigned bu = cu[0]; int bi = cix[0];
            #pragma unroll
            for (int k = 1; k < 4; ++k)
                if (better_u(cu[k], cix[k], bu, bi)) { bu = cu[k]; bi = cix[k]; }
            #pragma unroll
            for (int off = 32; off; off >>= 1) {
                unsigned ou = __shfl_xor(bu, off, 64);
                int      oi = __shfl_xor(bi, off, 64);
                if (better_u(ou, oi, bu, bi)) { bu = ou; bi = oi; }
            }
            if (lane == 0) { wcv[wave * K_ + p] = bu; wci[wave * K_ + p] = bi; }
            #pragma unroll
            for (int k = 0; k < 4; ++k)
                if (cix[k] == bi) cu[k] = 0u;
        }
        __syncthreads();

        // wave 0 merges the 160 wave-winners
        if (wave == 0) {
            unsigned c0u = wcv[lane],      c1u = wcv[64 + lane];
            int      c0i = wci[lane],      c1i = wci[64 + lane];
            unsigned c2u = (lane < 32) ? wcv[128 + lane] : 0u;
            int      c2i = (lane < 32) ? wci[128 + lane] : 0x7fffffff;
            for (int p = 0; p < K_; ++p) {
                unsigned bu = c0u; int bi = c0i;
                if (better_u(c1u, c1i, bu, bi)) { bu = c1u; bi = c1i; }
                if (better_u(c2u, c2i, bu, bi)) { bu = c2u; bi = c2i; }
                #pragma unroll
                for (int off = 32; off; off >>= 1) {
                    unsigned ou = __shfl_xor(bu, off, 64);
                    int      oi = __shfl_xor(bi, off, 64);
                    if (better_u(ou, oi, bu, bi)) { bu = ou; bi = oi; }
                }
                if (lane == 0) wstop[row * K_ + p] = bi;
                if (c0i == bi) c0u = 0u;
                if (c1i == bi) c1u = 0u;
                if (c2i == bi) c2u = 0u;
            }
        }
    } else {
        // exact fallback (never triggers for N(0,1)): wave0 re-scans row
        if (wave == 0) {
            unsigned tu[K_]; int tix[K_];
            #pragma unroll
            for (int s = 0; s < K_; ++s) { tu[s] = 0; tix[s] = 0x7fffffff; }
            const float* prow = pred + (size_t)row * V_;
            for (int i = lane; i < V_; i += 64) {
                unsigned u = umap(prow[i]);
                if (better_u(u, i, tu[K_-1], tix[K_-1])) {
                    tu[K_-1] = u; tix[K_-1] = i;
                    #pragma unroll
                    for (int s = K_-1; s > 0; --s)
                        if (better_u(tu[s], tix[s], tu[s-1], tix[s-1])) {
                            unsigned aa = tu[s]; tu[s] = tu[s-1]; tu[s-1] = aa;
                            int b2 = tix[s]; tix[s] = tix[s-1]; tix[s-1] = b2;
                        }
                }
            }
            for (int p = 0; p < K_; ++p) {
                unsigned bu = tu[0]; int bi = tix[0];
                #pragma unroll
                for (int s = 1; s < K_; ++s)
                    if (better_u(tu[s], tix[s], bu, bi)) { bu = tu[s]; bi = tix[s]; }
                #pragma unroll
                for (int off = 32; off; off >>= 1) {
                    unsigned ou = __shfl_xor(bu, off, 64);
                    int      oi = __shfl_xor(bi, off, 64);
                    if (better_u(ou, oi, bu, bi)) { bu = ou; bi = oi; }
                }
                if (lane == 0) wstop[row * K_ + p] = bi;
                #pragma unroll
                for (int s = 0; s < K_; ++s)
                    if (tix[s] == bi) tu[s] = 0;
            }
        }
    }
}

// == Kernel 2: FILL slice + XCD-local gather =================================
__global__ __launch_bounds__(NTG) void gather_kernel(
    const float* __restrict__ SC, const float* __restrict__ qkws,
    const int* __restrict__ nbt, const int* __restrict__ wstop,
    float* __restrict__ out, float* __restrict__ logws)
{
    const int r = blockIdx.x >> 3;
    const int ch = blockIdx.x & 7;
    const int lo = ch * SLICE, hi = lo + SLICE;
    const int tid = threadIdx.x;
    __shared__ int   topg[K_];
    __shared__ int   nid[N_];
    __shared__ __align__(16) float qk[D_];
    __shared__ int   list[N_];
    __shared__ int   lcnt;

    // fill this block's 1/8 f4-slice of the output row (stream-ordered
    // before finalize's scatter by kernel ordering)
    const float FILL = -18.420680743952367f;
    {
        int f4lo = (ch * S4) >> 3, f4hi = ((ch + 1) * S4) >> 3;
        float4 f4 = make_float4(FILL, FILL, FILL, FILL);
        float4* o4 = (float4*)(out + (size_t)r * S_);
        for (int i = f4lo + tid; i < f4hi; i += NTG) o4[i] = f4;
    }

    if (tid == 0) lcnt = 0;
    if (tid < K_) topg[tid] = wstop[r * K_ + tid];
    if (tid >= 64 && tid < 64 + D_ / 4)
        ((float4*)qk)[tid - 64] = ((const float4*)(qkws + (size_t)r * QKP))[tid - 64];
    __syncthreads();

    for (int i = tid; i < N_; i += NTG)
        nid[i] = nbt[topg[i >> 5] * G_ + (i & 31)];
    __syncthreads();

    for (int i = tid; i < N_; i += NTG) {
        int sv = nid[i];
        if (sv >= lo && sv < hi) { int p = atomicAdd(&lcnt, 1); list[p] = i; }
    }
    __syncthreads();
    const int c2 = lcnt;

    const float ISC = 0.08164965809277260327f;   // 1/sqrt(150)
    const float4* q4 = (const float4*)qk;
    for (int s = tid; s < 8 * c2; s += NTG) {
        int g = s >> 3, h = s & 7;
        int n = list[g];
        const float4* sc4 = (const float4*)(SC + (size_t)nid[n] * D_);
        int c0 = h * 9;
        float acc = 0.f;
        #pragma unroll
        for (int cc = 0; cc < 9; ++cc) {
            float4 av = sc4[c0 + cc];
            float4 bq = q4[c0 + cc];
            acc += av.x * bq.x + av.y * bq.y + av.z * bq.z + av.w * bq.w;
        }
        if (h < 3) {
            float4 av = sc4[72 + h];
            float4 bq = q4[72 + h];
            acc += av.x * bq.x + av.y * bq.y + av.z * bq.z + av.w * bq.w;
        }
        acc += __shfl_xor(acc, 1, 64);
        acc += __shfl_xor(acc, 2, 64);
        acc += __shfl_xor(acc, 4, 64);
        if (h == 0) logws[(size_t)r * N_ + n] = acc * ISC;
    }
}

// == Kernel 3: softmax + last-write-wins dup-kill + scatter ===================
__global__ __launch_bounds__(NTF) void finalize_kernel(
    const float* __restrict__ logws, const int* __restrict__ nbt,
    const int* __restrict__ wstop, float* __restrict__ out)
{
    const int row = blockIdx.x, tid = threadIdx.x;
    const int lane = tid & 63, wave = tid >> 6;
    __shared__ int   topg[K_];
    __shared__ float lg[N_];
    __shared__ int   nid[N_];
    __shared__ int   kills[N_];
    __shared__ float redA[6], redB[6];
    float* outrow = out + (size_t)row * S_;

    if (tid < K_) topg[tid] = wstop[row * K_ + tid];
    __syncthreads();
    if (tid < N_) {
        nid[tid] = nbt[topg[tid >> 5] * G_ + (tid & 31)];
        lg[tid]  = logws[(size_t)row * N_ + tid];
        kills[tid] = 0;
    }
    __syncthreads();

    float v = (tid < N_) ? lg[tid] : -INFINITY;
    float m = v;
    #pragma unroll
    for (int off = 32; off; off >>= 1) m = fmaxf(m, __shfl_xor(m, off, 64));
    if (lane == 0) redA[wave] = m;
    __syncthreads();
    m = redA[0];
    #pragma unroll
    for (int w = 1; w < 6; ++w) m = fmaxf(m, redA[w]);

    float ss = (tid < N_) ? expf(v - m) : 0.f;
    #pragma unroll
    for (int off = 32; off; off >>= 1) ss += __shfl_xor(ss, off, 64);
    if (lane == 0) redB[wave] = ss;
    __syncthreads();
    float tot = redB[0];
    #pragma unroll
    for (int w = 1; w < 6; ++w) tot += redB[w];
    float lsum = logf(tot);

    for (int s = tid; s < 4 * N_; s += NTF) {
        int n = s >> 2, cix = s & 3;
        int sidx = nid[n];
        int clo = cix * 80;
        int lo2 = (n + 1 > clo) ? n + 1 : clo;
        int hi2 = clo + 80;
        bool mt = false;
        #pragma unroll 4
        for (int n2 = lo2; n2 < hi2; ++n2) mt |= (nid[n2] == sidx);
        if (mt) kills[n] = 1;
    }
    __syncthreads();

    if (tid < N_ && !kills[tid]) outrow[nid[tid]] = (v - m) - lsum;
}

// ================= Fallback: fused single kernel (needs no ws) ===============
#define NWS 16
__device__ __forceinline__ bool better(float av, int ai, float bv, int bi) {
    return (av > bv) || (av == bv && ai < bi);
}
__global__ __launch_bounds__(NTS, 4) void selfatt_fused(
    const float* __restrict__ pred, const float* __restrict__ lc,
    const float* __restrict__ SC, const float* __restrict__ Wq,
    const float* __restrict__ Wk, const int* __restrict__ nbt,
    float* __restrict__ out)
{
    const int row = blockIdx.x, tid = threadIdx.x;
    const int lane = tid & 63, wave = tid >> 6;
    __shared__ float wcv[NWS * K_];
    __shared__ int   wci[NWS * K_];
    __shared__ int   topg[K_];
    __shared__ float lcs[D_];
    __shared__ float qs[DQKV_];
    __shared__ __align__(16) float qks[D_];
    __shared__ int   nidx[N_];
    __shared__ float lg[N_];
    __shared__ int   kills[N_];
    __shared__ float redA[NWS], redB[NWS];
    float* outrow = out + (size_t)row * S_;
    const float FILL = -18.420680743952367f;
    {
        float4 f4 = make_float4(FILL, FILL, FILL, FILL);
        float4* o4 = (float4*)outrow;
        #pragma unroll
        for (int k = 0; k < 7; ++k) { int i = tid + k * NTS; if (i < S4) o4[i] = f4; }
    }
    float tv[K_]; int ti[K_];
    #pragma unroll
    for (int s = 0; s < K_; ++s) { tv[s] = -INFINITY; ti[s] = 0x7fffffff; }
    {
        const float4* p4 = (const float4*)(pred + (size_t)row * V_);
        const float4 NEG = make_float4(-INFINITY, -INFINITY, -INFINITY, -INFINITY);
        float4 a[8]; int ib[8];
        #pragma unroll
        for (int u = 0; u < 8; ++u) {
            int i = tid + u * NTS;
            a[u]  = (i < V4) ? p4[i] : NEG;
            ib[u] = (i < V4) ? i * 4 : 0x7ffffff0;
        }
        #pragma unroll
        for (int u = 0; u < 8; ++u) {
            float x = a[u].x, y = a[u].y, z = a[u].z, w = a[u].w;
            float m4 = fmaxf(fmaxf(x, y), fmaxf(z, w));
            if (!(m4 < tv[K_-1])) {
                float vals[4] = {x, y, z, w};
                #pragma unroll
                for (int cc = 0; cc < 4; ++cc) {
                    float val = vals[cc];
                    int   idx = ib[u] + cc;
                    if (better(val, idx, tv[K_-1], ti[K_-1])) {
                        tv[K_-1] = val; ti[K_-1] = idx;
                        #pragma unroll
                        for (int s = K_-1; s > 0; --s) {
                            if (better(tv[s], ti[s], tv[s-1], ti[s-1])) {
                                float fx = tv[s]; tv[s] = tv[s-1]; tv[s-1] = fx;
                                int   iy = ti[s]; ti[s] = ti[s-1]; ti[s-1] = iy;
                            }
                        }
                    }
                }
            }
        }
    }
    for (int p = 0; p < K_; ++p) {
        float bv = tv[0]; int bi = ti[0];
        #pragma unroll
        for (int s = 1; s < K_; ++s)
            if (better(tv[s], ti[s], bv, bi)) { bv = tv[s]; bi = ti[s]; }
        #pragma unroll
        for (int off = 32; off; off >>= 1) {
            float ov = __shfl_xor(bv, off, 64);
            int   oi = __shfl_xor(bi, off, 64);
            if (better(ov, oi, bv, bi)) { bv = ov; bi = oi; }
        }
        if (lane == 0) { wcv[wave * K_ + p] = bv; wci[wave * K_ + p] = bi; }
        #pragma unroll
        for (int s = 0; s < K_; ++s)
            if (ti[s] == bi) tv[s] = -INFINITY;
    }
    __syncthreads();
    if (wave == 0) {
        float c0v = wcv[lane],      c1v = wcv[64 + lane];
        int   c0i = wci[lane],      c1i = wci[64 + lane];
        float c2v = (lane < 32) ? wcv[128 + lane] : -INFINITY;
        int   c2i = (lane < 32) ? wci[128 + lane] : 0x7fffffff;
        for (int p = 0; p < K_; ++p) {
            float bv = c0v; int bi = c0i;
            if (better(c1v, c1i, bv, bi)) { bv = c1v; bi = c1i; }
            if (better(c2v, c2i, bv, bi)) { bv = c2v; bi = c2i; }
            #pragma unroll
            for (int off = 32; off; off >>= 1) {
                float ov = __shfl_xor(bv, off, 64);
                int   oi = __shfl_xor(bi, off, 64);
                if (better(ov, oi, bv, bi)) { bv = ov; bi = oi; }
            }
            if (lane == 0) topg[p] = bi;
            if (c0i == bi) c0v = -INFINITY;
            if (c1i == bi) c1v = -INFINITY;
            if (c2i == bi) c2v = -INFINITY;
        }
    }
    __syncthreads();
    if (tid < N_) { int g = topg[tid >> 5]; nidx[tid] = nbt[g * G_ + (tid & 31)]; }
    else if (tid < 2 * N_) kills[tid - N_] = 0;
    else if (tid >= 640 && tid < 640 + D_) lcs[tid - 640] = lc[(size_t)row * D_ + (tid - 640)];
    __syncthreads();
    if (tid < 600) {
        int j = tid >> 2, h = tid & 3;
        int d0 = h * 75;
        const float* wp = Wq + (size_t)d0 * DQKV_ + j;
        float acc = 0.f;
        #pragma unroll 5
        for (int dd = 0; dd < 75; ++dd) acc += lcs[d0 + dd] * wp[(size_t)dd * DQKV_];
        acc += __shfl_xor(acc, 1, 64);
        acc += __shfl_xor(acc, 2, 64);
        if (h == 0) qs[j] = acc;
    } else {
        int t0 = tid - 600;
        for (int s = t0; s < 4 * N_; s += 424) {
            int n = s >> 2, cc = s & 3;
            int sidx = nidx[n];
            int clo = cc * 80;
            int lo = (n + 1 > clo) ? n + 1 : clo;
            int hi = clo + 80;
            bool mt = false;
            #pragma unroll 4
            for (int n2 = lo; n2 < hi; ++n2) mt |= (nidx[n2] == sidx);
            if (mt) kills[n] = 1;
        }
    }
    __syncthreads();
    if (tid < 600) {
        int d = tid >> 1, h = tid & 1;
        int j0 = h * 75;
        const float* wrow = Wk + (size_t)d * DQKV_ + j0;
        float acc = 0.f;
        #pragma unroll 5
        for (int jj = 0; jj < 75; ++jj) acc += wrow[jj] * qs[j0 + jj];
        acc += __shfl_xor(acc, 1, 64);
        if (h == 0) qks[d] = acc;
    }
    __syncthreads();
    const float ISC = 0.08164965809277260327f;
    const float4* q4 = (const float4*)qks;
    for (int s = tid; s < 8 * N_; s += NTS) {
        int n = s >> 3, h = s & 7;
        const float4* sc4 = (const float4*)(SC + (size_t)nidx[n] * D_);
        int c0 = h * 9;
        float acc = 0.f;
        #pragma unroll
        for (int cc = 0; cc < 9; ++cc) {
            float4 a = sc4[c0 + cc];
            float4 b = q4[c0 + cc];
            acc += a.x * b.x + a.y * b.y + a.z * b.z + a.w * b.w;
        }
        if (h < 3) {
            float4 a = sc4[72 + h];
            float4 b = q4[72 + h];
            acc += a.x * b.x + a.y * b.y + a.z * b.z + a.w * b.w;
        }
        acc += __shfl_xor(acc, 1, 64);
        acc += __shfl_xor(acc, 2, 64);
        acc += __shfl_xor(acc, 4, 64);
        if (h == 0) lg[n] = acc * ISC;
    }
    __syncthreads();
    float v = (tid < N_) ? lg[tid] : -INFINITY;
    float m = v;
    #pragma unroll
    for (int off = 32; off; off >>= 1) m = fmaxf(m, __shfl_xor(m, off, 64));
    if (lane == 0) redA[wave] = m;
    __syncthreads();
    m = redA[0];
    #pragma unroll
    for (int w = 1; w < NWS; ++w) m = fmaxf(m, redA[w]);
    float e = (tid < N_) ? expf(v - m) : 0.f;
    float ss = e;
    #pragma unroll
    for (int off = 32; off; off >>= 1) ss += __shfl_xor(ss, off, 64);
    if (lane == 0) redB[wave] = ss;
    __syncthreads();
    float tot = redB[0];
    #pragma unroll
    for (int w = 1; w < NWS; ++w) tot += redB[w];
    float lsum = logf(tot);
    if (tid < N_ && !kills[tid]) outrow[nidx[tid]] = (v - m) - lsum;
}

extern "C" void kernel_launch(void* const* d_in, const int* in_sizes, int n_in,
                              void* d_out, int out_size, void* d_ws, size_t ws_size,
                              hipStream_t stream) {
    const float* pred = (const float*)d_in[0];
    const float* lc   = (const float*)d_in[1];
    const float* SC   = (const float*)d_in[2];
    const float* Wq   = (const float*)d_in[3];
    const float* Wk   = (const float*)d_in[4];
    const int*   nbt  = (const int*)d_in[5];
    float* out = (float*)d_out;

    const int nrows = T_ * B_;
    const size_t nQK = (size_t)nrows * QKP;            // floats
    const size_t nLG = (size_t)nrows * N_;             // floats
    const size_t nTP = (size_t)nrows * K_;             // ints (wstop)
    const size_t need = (nQK + nLG) * sizeof(float) + nTP * sizeof(int);

    if (ws_size >= need) {
        float* qkws  = (float*)d_ws;
        float* logws = qkws + nQK;
        int*   wstop = (int*)(logws + nLG);
        stage1_kernel<<<dim3(nrows * 2), dim3(NTS), 0, stream>>>(
            pred, lc, Wq, Wk, wstop, qkws);
        gather_kernel<<<dim3(nrows * 8), dim3(NTG), 0, stream>>>(
            SC, qkws, nbt, wstop, out, logws);
        finalize_kernel<<<dim3(nrows), dim3(NTF), 0, stream>>>(
            logws, nbt, wstop, out);
    } else {
        selfatt_fused<<<dim3(nrows), dim3(NTS), 0, stream>>>(
            pred, lc, SC, Wq, Wk, nbt, out);
    }
}